// Round 4
// baseline (1522.927 us; speedup 1.0000x reference)
//
#include <hip/hip_runtime.h>
#include <hip/hip_fp16.h>
#include <cstdint>

#define T_LEN 128
#define DA    16
#define DZ    32
#define HH    128

__device__ __forceinline__ float sigm(float x){ return 1.0f/(1.0f + __expf(-x)); }
__device__ __forceinline__ float tanh_f(float x){ return 1.0f - 2.0f/(__expf(2.0f*x)+1.0f); }
__device__ __forceinline__ float dot4(float4 a, float4 b){ return a.x*b.x + a.y*b.y + a.z*b.z + a.w*b.w; }

typedef _Float16 h2v __attribute__((ext_vector_type(2)));
__device__ __forceinline__ float fdot2(uint32_t w, uint32_t h, float acc){
  union{uint32_t u; h2v v;} a, b; a.u = w; b.u = h;
  return __builtin_amdgcn_fdot2(a.v, b.v, acc, false);
}
__device__ __forceinline__ uint32_t packh2(float x, float y){
  return (uint32_t)__half_as_ushort(__float2half(x)) |
         ((uint32_t)__half_as_ushort(__float2half(y)) << 16);
}

// LDS-only barrier: drain LDS pipe (write visibility), then raw s_barrier.
// Does NOT drain vmcnt, so global prefetch loads stay in flight.
#define BAR() do { asm volatile("s_waitcnt lgkmcnt(0)" ::: "memory"); \
                   __builtin_amdgcn_s_barrier(); } while (0)

// ws layout (32-bit words):
//   [0,4096)         Wih0h fp16-pairs: word idx (m*512+g)*4+q, m<2, q<4 -> w[g][8m+2q..+1]
//   [4096,36864)     Whh0h: m<16
//   [36864,69632)    Wih1h: m<16
//   [69632,102400)   Whh1h: m<16
//   [102400,102912)  b0 = bih0+bhh0 (f32)
//   [102912,103424)  b1 = bih1+bhh1 (f32)
//   [103424,300032)  alpha (512,128,3) f32

__global__ void prep_kernel(const float* __restrict__ Wih0, const float* __restrict__ Whh0,
                            const float* __restrict__ bih0, const float* __restrict__ bhh0,
                            const float* __restrict__ Wih1, const float* __restrict__ Whh1,
                            const float* __restrict__ bih1, const float* __restrict__ bhh1,
                            uint32_t* __restrict__ ws) {
  int idx = blockIdx.x*256 + threadIdx.x;
  if (idx < 4096) {
    int q = idx & 3, g = (idx >> 2) & 511, m = idx >> 11;
    int k0 = 8*m + 2*q;
    ws[idx] = packh2(Wih0[g*DA + k0], Wih0[g*DA + k0 + 1]);
  } else if (idx < 36864) {
    int f = idx - 4096;
    int q = f & 3, g = (f >> 2) & 511, m = f >> 11;
    int k0 = 8*m + 2*q;
    ws[idx] = packh2(Whh0[g*HH + k0], Whh0[g*HH + k0 + 1]);
  } else if (idx < 69632) {
    int f = idx - 36864;
    int q = f & 3, g = (f >> 2) & 511, m = f >> 11;
    int k0 = 8*m + 2*q;
    ws[idx] = packh2(Wih1[g*HH + k0], Wih1[g*HH + k0 + 1]);
  } else if (idx < 102400) {
    int f = idx - 69632;
    int q = f & 3, g = (f >> 2) & 511, m = f >> 11;
    int k0 = 8*m + 2*q;
    ws[idx] = packh2(Whh1[g*HH + k0], Whh1[g*HH + k0 + 1]);
  } else if (idx < 102912) {
    int j = idx - 102400;
    ((float*)ws)[idx] = bih0[j] + bhh0[j];
  } else if (idx < 103424) {
    int j = idx - 102912;
    ((float*)ws)[idx] = bih1[j] + bhh1[j];
  }
}

// Persistent 2-layer LSTM (register-resident weights + dual-row).
// Round-4: fixed the r2 typo in the Whh1 g1a/g1b accumulation.
__global__ __launch_bounds__(512, 2) void lstm_kernel(
    const float* __restrict__ a, const float* __restrict__ a0,
    const uint32_t* __restrict__ wsw, const float* __restrict__ Wlin,
    const float* __restrict__ blin, float* __restrict__ alpha_out) {
  const uint4* Wih0p = (const uint4*)(wsw);
  const uint4* Whh0p = (const uint4*)(wsw + 4096);
  const uint4* Wih1p = (const uint4*)(wsw + 36864);
  const uint4* Whh1p = (const uint4*)(wsw + 69632);
  const float* b0v = (const float*)(wsw + 102400);
  const float* b1v = (const float*)(wsw + 102912);

  __shared__ __align__(16) uint32_t sxh[2][T_LEN][8];
  __shared__ __align__(16) uint32_t sh0h[2][64];
  __shared__ __align__(16) uint32_t sh1h[2][64];
  __shared__ float gates[2][4*HH];

  int tid = threadIdx.x;
  int lane = tid & 63;
  int wv = tid >> 6;
  int bb = blockIdx.x * 2;

  uint4 wi0[2], wh0[16], wi1[16], wh1[16];
  #pragma unroll
  for (int m = 0; m < 2; ++m)  wi0[m] = Wih0p[m*512 + tid];
  #pragma unroll
  for (int m = 0; m < 16; ++m) wh0[m] = Whh0p[m*512 + tid];
  #pragma unroll
  for (int m = 0; m < 16; ++m) wi1[m] = Wih1p[m*512 + tid];
  #pragma unroll
  for (int m = 0; m < 16; ++m) wh1[m] = Whh1p[m*512 + tid];
  float bi0 = b0v[tid], bi1 = b1v[tid];

  for (int i = tid; i < 2*T_LEN*8; i += 512) {
    int r = i / (T_LEN*8), rem = i % (T_LEN*8), t = rem >> 3, p = rem & 7;
    float x0, x1;
    if (t == 0) { x0 = a0[2*p]; x1 = a0[2*p+1]; }
    else {
      const float* src = a + ((size_t)(bb + r)*T_LEN + (t-1))*DA;
      x0 = src[2*p]; x1 = src[2*p+1];
    }
    sxh[r][t][p] = packh2(x0, x1);
  }
  float wl00 = Wlin[0*HH + 2*lane], wl01 = Wlin[0*HH + 2*lane+1];
  float wl10 = Wlin[1*HH + 2*lane], wl11 = Wlin[1*HH + 2*lane+1];
  float wl20 = Wlin[2*HH + 2*lane], wl21 = Wlin[2*HH + 2*lane+1];
  float bl0 = blin[0], bl1 = blin[1], bl2 = blin[2];
  float c00 = 0.f, c01 = 0.f, c10 = 0.f, c11 = 0.f;
  if (tid < 128) { sh0h[wv][lane] = 0u; sh1h[wv][lane] = 0u; }
  __syncthreads();

  #pragma unroll 1
  for (int t = 0; t < T_LEN; ++t) {
    {
      float g0a = bi0, g0b = 0.f, g1a = bi0, g1b = 0.f;
      uint4 xA0 = *(const uint4*)&sxh[0][t][0];
      uint4 xA1 = *(const uint4*)&sxh[0][t][4];
      uint4 xB0 = *(const uint4*)&sxh[1][t][0];
      uint4 xB1 = *(const uint4*)&sxh[1][t][4];
      g0a = fdot2(wi0[0].x, xA0.x, g0a); g0b = fdot2(wi0[0].y, xA0.y, g0b);
      g0a = fdot2(wi0[0].z, xA0.z, g0a); g0b = fdot2(wi0[0].w, xA0.w, g0b);
      g0a = fdot2(wi0[1].x, xA1.x, g0a); g0b = fdot2(wi0[1].y, xA1.y, g0b);
      g0a = fdot2(wi0[1].z, xA1.z, g0a); g0b = fdot2(wi0[1].w, xA1.w, g0b);
      g1a = fdot2(wi0[0].x, xB0.x, g1a); g1b = fdot2(wi0[0].y, xB0.y, g1b);
      g1a = fdot2(wi0[0].z, xB0.z, g1a); g1b = fdot2(wi0[0].w, xB0.w, g1b);
      g1a = fdot2(wi0[1].x, xB1.x, g1a); g1b = fdot2(wi0[1].y, xB1.y, g1b);
      g1a = fdot2(wi0[1].z, xB1.z, g1a); g1b = fdot2(wi0[1].w, xB1.w, g1b);
      #pragma unroll
      for (int m = 0; m < 16; ++m) {
        uint4 w = wh0[m];
        uint4 hA = *(const uint4*)&sh0h[0][4*m];
        uint4 hB = *(const uint4*)&sh0h[1][4*m];
        g0a = fdot2(w.x, hA.x, g0a); g0b = fdot2(w.y, hA.y, g0b);
        g0a = fdot2(w.z, hA.z, g0a); g0b = fdot2(w.w, hA.w, g0b);
        g1a = fdot2(w.x, hB.x, g1a); g1b = fdot2(w.y, hB.y, g1b);
        g1a = fdot2(w.z, hB.z, g1a); g1b = fdot2(w.w, hB.w, g1b);
      }
      gates[0][tid] = g0a + g0b;
      gates[1][tid] = g1a + g1b;
    }
    __syncthreads();                                   // B1
    if (tid < 128) {
      int j0 = 2*lane, j1 = j0 + 1;
      float i0 = gates[wv][j0],      f0 = gates[wv][j0+HH],
            q0 = gates[wv][j0+2*HH], o0 = gates[wv][j0+3*HH];
      c00 = sigm(f0)*c00 + sigm(i0)*tanh_f(q0);
      float hv0 = sigm(o0)*tanh_f(c00);
      float i1 = gates[wv][j1],      f1 = gates[wv][j1+HH],
            q1 = gates[wv][j1+2*HH], o1 = gates[wv][j1+3*HH];
      c01 = sigm(f1)*c01 + sigm(i1)*tanh_f(q1);
      float hv1 = sigm(o1)*tanh_f(c01);
      sh0h[wv][lane] = packh2(hv0, hv1);
    }
    __syncthreads();                                   // B2
    {
      float g0a = bi1, g0b = 0.f, g1a = bi1, g1b = 0.f;
      #pragma unroll
      for (int m = 0; m < 16; ++m) {
        uint4 w = wi1[m];
        uint4 hA = *(const uint4*)&sh0h[0][4*m];
        uint4 hB = *(const uint4*)&sh0h[1][4*m];
        g0a = fdot2(w.x, hA.x, g0a); g0b = fdot2(w.y, hA.y, g0b);
        g0a = fdot2(w.z, hA.z, g0a); g0b = fdot2(w.w, hA.w, g0b);
        g1a = fdot2(w.x, hB.x, g1a); g1b = fdot2(w.y, hB.y, g1b);
        g1a = fdot2(w.z, hB.z, g1a); g1b = fdot2(w.w, hB.w, g1b);
      }
      #pragma unroll
      for (int m = 0; m < 16; ++m) {
        uint4 w = wh1[m];
        uint4 hA = *(const uint4*)&sh1h[0][4*m];
        uint4 hB = *(const uint4*)&sh1h[1][4*m];
        g0a = fdot2(w.x, hA.x, g0a); g0b = fdot2(w.y, hA.y, g0b);
        g0a = fdot2(w.z, hA.z, g0a); g0b = fdot2(w.w, hA.w, g0b);
        g1a = fdot2(w.x, hB.x, g1a); g1b = fdot2(w.y, hB.y, g1b);
        g1a = fdot2(w.z, hB.z, g1a); g1b = fdot2(w.w, hB.w, g1b);
      }
      gates[0][tid] = g0a + g0b;
      gates[1][tid] = g1a + g1b;
    }
    __syncthreads();                                   // B3
    float hv0 = 0.f, hv1 = 0.f;
    if (tid < 128) {
      int j0 = 2*lane, j1 = j0 + 1;
      float i0 = gates[wv][j0],      f0 = gates[wv][j0+HH],
            q0 = gates[wv][j0+2*HH], o0 = gates[wv][j0+3*HH];
      c10 = sigm(f0)*c10 + sigm(i0)*tanh_f(q0);
      hv0 = sigm(o0)*tanh_f(c10);
      float i1 = gates[wv][j1],      f1 = gates[wv][j1+HH],
            q1 = gates[wv][j1+2*HH], o1 = gates[wv][j1+3*HH];
      c11 = sigm(f1)*c11 + sigm(i1)*tanh_f(q1);
      hv1 = sigm(o1)*tanh_f(c11);
      sh1h[wv][lane] = packh2(hv0, hv1);
    }
    __syncthreads();                                   // B4
    if (tid < 128) {
      float p0 = hv0*wl00 + hv1*wl01;
      float p1 = hv0*wl10 + hv1*wl11;
      float p2 = hv0*wl20 + hv1*wl21;
      #pragma unroll
      for (int off = 32; off > 0; off >>= 1) {
        p0 += __shfl_down(p0, off); p1 += __shfl_down(p1, off); p2 += __shfl_down(p2, off);
      }
      if (lane == 0) {
        float l0 = p0 + bl0, l1 = p1 + bl1, l2 = p2 + bl2;
        float mx = fmaxf(l0, fmaxf(l1, l2));
        float e0=__expf(l0-mx), e1=__expf(l1-mx), e2=__expf(l2-mx);
        float inv = 1.0f/(e0+e1+e2);
        float* dst = alpha_out + (((size_t)(bb+wv))*T_LEN + t)*3;
        dst[0]=e0*inv; dst[1]=e1*inv; dst[2]=e2*inv;
      }
    }
  }
}

// Kalman scan v8: b128-instruction-count reduction. Rounds 1-3 established
// wall ~= 12.6 cyc x (b128-class LDS wave-instrs), i.e. the DS pipe at its
// measured per-instruction ceiling. Cuts (all layout-preserving):
//  - width-8 output strips: (i = tid&31, strip = tid>>5) so the row-operand
//    read amortizes 2x; per-instr B-row broadcasts have 2 distinct addrs at
//    row-delta 8 -> same-bank 2-way, which is free (m136).
//  - symmetry row.row forms: Sp2 symmetric => T2[r][k]=dot(Am[r],Sp2[k]),
//    Sg'[i][j]=dot(T2[i],Am[j]) -> AmT deleted. Sp2[i][j]=Sg[i][j]-
//    dot(Kg[i],Nn[j]), Kg[i][j]=dot(Nn[i],Sinv[j]) -> NnT deleted.
//  - mu+/mu_pred on wave 2 parallel to Sp2/Sg' phases.
// ~720 -> ~560 b128/block-step; predict 851 -> ~690 us.
__global__ __launch_bounds__(256) void kalman_kernel(
    const float* __restrict__ a, const float* __restrict__ A,
    const float* __restrict__ C, const float* __restrict__ alpha,
    float* __restrict__ out) {
  __shared__ __align__(16) float Sg[DZ][36];
  __shared__ __align__(16) float Am[DZ][36];
  __shared__ __align__(16) float Cm[DA][36];
  __shared__ __align__(16) float Nn[DZ][20];
  __shared__ __align__(16) float Aug[DA][36];
  __shared__ __align__(16) float Kg[DZ][20];
  __shared__ __align__(16) float Sp2[DZ][36];
  __shared__ __align__(16) float T2m[DZ][36];
  __shared__ __align__(16) float sa[T_LEN][DA];
  __shared__ float salpha[T_LEN*3];
  __shared__ __align__(16) float muv[DZ], mun[DZ], rv[DA];

  int tid = threadIdx.x;
  int b = blockIdx.x;

  for (int e = tid; e < T_LEN*DA; e += 256) (&sa[0][0])[e] = a[(size_t)b*T_LEN*DA + e];
  for (int e = tid; e < T_LEN*3; e += 256) salpha[e] = alpha[(size_t)b*T_LEN*3 + e];
  for (int e = tid; e < DZ*36; e += 256) (&Sg[0][0])[e] = 0.0f;
  __syncthreads();
  if (tid < DZ) { Sg[tid][tid] = 1.0f; muv[tid] = 0.0f; }

  const int i8 = tid >> 3, j4m = (tid & 7) * 4;
  const int i32 = tid & 31;            // row for width-8/width-4 phases
  const int s8  = (tid >> 5) * 8;      // 8-wide strip base (tid<128 -> 0,8,16,24)
  const int s4  = (tid >> 5) * 4;      // 4-wide strip base (tid<128 -> 0,4,8,12)

  const float4* A4 = (const float4*)A;
  const float4* C4 = (const float4*)C;
  float4 pA0 = A4[(0*T_LEN + 1)*256 + tid];
  float4 pA1 = A4[(1*T_LEN + 1)*256 + tid];
  float4 pA2 = A4[(2*T_LEN + 1)*256 + tid];
  float4 pC0, pC1, pC2;
  if (tid < 128) {
    pC0 = C4[(0*T_LEN + 0)*128 + tid];
    pC1 = C4[(1*T_LEN + 0)*128 + tid];
    pC2 = C4[(2*T_LEN + 0)*128 + tid];
  }
  __syncthreads();

  #pragma unroll 1
  for (int t = 0; t < T_LEN; ++t) {
    int ta = (t < T_LEN-1) ? t+1 : t;
    float b10 = salpha[ta*3+0], b11 = salpha[ta*3+1], b12 = salpha[ta*3+2];
    float b00 = salpha[t*3+0],  b01 = salpha[t*3+1],  b02 = salpha[t*3+2];

    // ---- mix: Am (alpha[ta]), Cm (alpha[t]); issue next prefetch ----
    {
      float4 v;
      v.x = b10*pA0.x + b11*pA1.x + b12*pA2.x;
      v.y = b10*pA0.y + b11*pA1.y + b12*pA2.y;
      v.z = b10*pA0.z + b11*pA1.z + b12*pA2.z;
      v.w = b10*pA0.w + b11*pA1.w + b12*pA2.w;
      *(float4*)&Am[i8][j4m] = v;
      if (tid < 128) {
        float4 c;
        c.x = b00*pC0.x + b01*pC1.x + b02*pC2.x;
        c.y = b00*pC0.y + b01*pC1.y + b02*pC2.y;
        c.z = b00*pC0.z + b01*pC1.z + b02*pC2.z;
        c.w = b00*pC0.w + b01*pC1.w + b02*pC2.w;
        *(float4*)&Cm[tid>>3][(tid&7)*4] = c;
      }
      int tn  = (t+1 < T_LEN) ? t+1 : T_LEN-1;
      int tan = (tn < T_LEN-1) ? tn+1 : tn;
      pA0 = A4[(0*T_LEN + tan)*256 + tid];
      pA1 = A4[(1*T_LEN + tan)*256 + tid];
      pA2 = A4[(2*T_LEN + tan)*256 + tid];
      if (tid < 128) {
        pC0 = C4[(0*T_LEN + tn)*128 + tid];
        pC1 = C4[(1*T_LEN + tn)*128 + tid];
        pC2 = C4[(2*T_LEN + tn)*128 + tid];
      }
    }
    BAR();                                             // B0

    // ---- N = Sg*Cm^T row.row (wave 0, width-8); r on wave 3 ----
    if (tid < 64) {
      float4 sg[8];
      #pragma unroll
      for (int k4 = 0; k4 < 8; ++k4) sg[k4] = *(const float4*)&Sg[i32][4*k4];
      float acc[8];
      #pragma unroll
      for (int c = 0; c < 8; ++c) {
        float d = 0.f;
        #pragma unroll
        for (int k4 = 0; k4 < 8; ++k4)
          d += dot4(sg[k4], *(const float4*)&Cm[s8+c][4*k4]);
        acc[c] = d;
      }
      *(float4*)&Nn[i32][s8]   = make_float4(acc[0],acc[1],acc[2],acc[3]);
      *(float4*)&Nn[i32][s8+4] = make_float4(acc[4],acc[5],acc[6],acc[7]);
    } else if (tid >= 192 && tid < 192 + DA) {
      int j = tid - 192;
      float acc = sa[t][j];
      #pragma unroll
      for (int k4 = 0; k4 < 8; ++k4)
        acc -= dot4(*(const float4*)&Cm[j][4*k4], *(const float4*)&muv[4*k4]);
      rv[j] = acc;
    }
    BAR();                                             // B1

    // ---- Aug = [Cm*N + R | I] (wave 0, width-4, 4-row broadcast of Nn) ----
    if (tid < 64) {
      int i = tid & 15, j4 = (tid >> 4) * 4;
      float4 cm[8];
      #pragma unroll
      for (int k4 = 0; k4 < 8; ++k4) cm[k4] = *(const float4*)&Cm[i][4*k4];
      float4 acc = make_float4(0.f,0.f,0.f,0.f);
      #pragma unroll
      for (int k4 = 0; k4 < 8; ++k4) {
        float4 n0 = *(const float4*)&Nn[4*k4+0][j4];
        float4 n1 = *(const float4*)&Nn[4*k4+1][j4];
        float4 n2 = *(const float4*)&Nn[4*k4+2][j4];
        float4 n3 = *(const float4*)&Nn[4*k4+3][j4];
        acc.x += cm[k4].x*n0.x + cm[k4].y*n1.x + cm[k4].z*n2.x + cm[k4].w*n3.x;
        acc.y += cm[k4].x*n0.y + cm[k4].y*n1.y + cm[k4].z*n2.y + cm[k4].w*n3.y;
        acc.z += cm[k4].x*n0.z + cm[k4].y*n1.z + cm[k4].z*n2.z + cm[k4].w*n3.z;
        acc.w += cm[k4].x*n0.w + cm[k4].y*n1.w + cm[k4].z*n2.w + cm[k4].w*n3.w;
      }
      acc.x += (i == j4+0) ? 0.01f : 0.f;
      acc.y += (i == j4+1) ? 0.01f : 0.f;
      acc.z += (i == j4+2) ? 0.01f : 0.f;
      acc.w += (i == j4+3) ? 0.01f : 0.f;
      *(float4*)&Aug[i][j4] = acc;
      *(float4*)&Aug[i][16+j4] = make_float4(
          (i==j4+0)?1.f:0.f, (i==j4+1)?1.f:0.f,
          (i==j4+2)?1.f:0.f, (i==j4+3)?1.f:0.f);
    }
    BAR();                                             // B2

    // ---- GJ: wave-synchronous Gauss-Jordan (wave 0) ----
    if (tid < 64) {
      int lane = tid;
      int r = lane >> 2, cb = lane & 3;
      float v[8];
      #pragma unroll
      for (int j = 0; j < 8; ++j) v[j] = Aug[r][cb*8 + j];
      #define GJ_PIVOT(P, CTRL)                                                \
      {                                                                        \
        float App = __int_as_float(__builtin_amdgcn_readlane(                  \
                      __float_as_int(v[(P) & 7]), ((P) << 2) | ((P) >> 3)));   \
        float fv  = __int_as_float(__builtin_amdgcn_mov_dpp(                   \
                      __float_as_int(v[(P) & 7]), (CTRL), 0xf, 0xf, true));    \
        float prow[8];                                                         \
        _Pragma("unroll")                                                      \
        for (int j = 0; j < 8; ++j) prow[j] = __shfl(v[j], ((P) << 2) | cb, 64); \
        float pinv = 1.0f / App;                                               \
        if (r == (P)) {                                                        \
          _Pragma("unroll")                                                    \
          for (int j = 0; j < 8; ++j) v[j] *= pinv;                            \
        } else {                                                               \
          float fp = fv * pinv;                                                \
          _Pragma("unroll")                                                    \
          for (int j = 0; j < 8; ++j) v[j] -= fp * prow[j];                    \
        }                                                                      \
      }
      GJ_PIVOT(0, 0x00)  GJ_PIVOT(1, 0x00)  GJ_PIVOT(2, 0x00)  GJ_PIVOT(3, 0x00)
      GJ_PIVOT(4, 0x00)  GJ_PIVOT(5, 0x00)  GJ_PIVOT(6, 0x00)  GJ_PIVOT(7, 0x00)
      GJ_PIVOT(8, 0x55)  GJ_PIVOT(9, 0x55)  GJ_PIVOT(10, 0x55) GJ_PIVOT(11, 0x55)
      GJ_PIVOT(12, 0x55) GJ_PIVOT(13, 0x55) GJ_PIVOT(14, 0x55) GJ_PIVOT(15, 0x55)
      #undef GJ_PIVOT
      if (cb >= 2) {
        #pragma unroll
        for (int j = 0; j < 8; ++j) Aug[r][cb*8 + j] = v[j];
      }
    }
    BAR();                                             // B3

    // ---- Kg = Nn*Sinv row.row (waves 0-1, width-4; Sinv symmetric) ----
    if (tid < 128) {
      float4 nn[4];
      #pragma unroll
      for (int k4 = 0; k4 < 4; ++k4) nn[k4] = *(const float4*)&Nn[i32][4*k4];
      float acc[4];
      #pragma unroll
      for (int c = 0; c < 4; ++c) {
        float d = 0.f;
        #pragma unroll
        for (int k4 = 0; k4 < 4; ++k4)
          d += dot4(nn[k4], *(const float4*)&Aug[s4+c][16+4*k4]);
        acc[c] = d;
      }
      *(float4*)&Kg[i32][s4] = make_float4(acc[0],acc[1],acc[2],acc[3]);
    }
    BAR();                                             // B4

    // ---- Sp2 = Sg - Kg*Nn^T row.row (waves 0-1, width-8); mu+ on wave 2 ----
    if (tid < 128) {
      float4 kg[4];
      #pragma unroll
      for (int k4 = 0; k4 < 4; ++k4) kg[k4] = *(const float4*)&Kg[i32][4*k4];
      float4 sg0 = *(const float4*)&Sg[i32][s8];
      float4 sg1 = *(const float4*)&Sg[i32][s8+4];
      float acc[8];
      #pragma unroll
      for (int c = 0; c < 8; ++c) {
        float d = 0.f;
        #pragma unroll
        for (int k4 = 0; k4 < 4; ++k4)
          d += dot4(kg[k4], *(const float4*)&Nn[s8+c][4*k4]);
        acc[c] = d;
      }
      *(float4*)&Sp2[i32][s8] =
          make_float4(sg0.x-acc[0], sg0.y-acc[1], sg0.z-acc[2], sg0.w-acc[3]);
      *(float4*)&Sp2[i32][s8+4] =
          make_float4(sg1.x-acc[4], sg1.y-acc[5], sg1.z-acc[6], sg1.w-acc[7]);
    } else if (tid < 128 + DZ) {
      int j = tid - 128;
      float m = muv[j];
      #pragma unroll
      for (int k4 = 0; k4 < 4; ++k4)
        m += dot4(*(const float4*)&Kg[j][4*k4], *(const float4*)&rv[4*k4]);
      mun[j] = m;
      out[((size_t)b*T_LEN + t)*DZ + j] = m;
    }
    BAR();                                             // B5

    // ---- T2[r][k] = dot(Am[r], Sp2[k]) (Sp2 symmetric) waves 0-1, width-8 ----
    if (tid < 128) {
      float4 am[8];
      #pragma unroll
      for (int k4 = 0; k4 < 8; ++k4) am[k4] = *(const float4*)&Am[i32][4*k4];
      float acc[8];
      #pragma unroll
      for (int c = 0; c < 8; ++c) {
        float d = 0.f;
        #pragma unroll
        for (int k4 = 0; k4 < 8; ++k4)
          d += dot4(am[k4], *(const float4*)&Sp2[s8+c][4*k4]);
        acc[c] = d;
      }
      *(float4*)&T2m[i32][s8]   = make_float4(acc[0],acc[1],acc[2],acc[3]);
      *(float4*)&T2m[i32][s8+4] = make_float4(acc[4],acc[5],acc[6],acc[7]);
    }
    BAR();                                             // B6

    // ---- Sg' = T2*Am^T + Q row.row (waves 0-1, width-8); mu_pred wave 2 ----
    if (tid < 128) {
      float4 t2[8];
      #pragma unroll
      for (int k4 = 0; k4 < 8; ++k4) t2[k4] = *(const float4*)&T2m[i32][4*k4];
      float acc[8];
      #pragma unroll
      for (int c = 0; c < 8; ++c) {
        float d = 0.f;
        #pragma unroll
        for (int k4 = 0; k4 < 8; ++k4)
          d += dot4(t2[k4], *(const float4*)&Am[s8+c][4*k4]);
        if (i32 == s8+c) d += 0.01f;
        acc[c] = d;
      }
      *(float4*)&Sg[i32][s8]   = make_float4(acc[0],acc[1],acc[2],acc[3]);
      *(float4*)&Sg[i32][s8+4] = make_float4(acc[4],acc[5],acc[6],acc[7]);
    } else if (tid < 128 + DZ) {
      int j = tid - 128;
      float m = 0.0f;
      #pragma unroll
      for (int k4 = 0; k4 < 8; ++k4)
        m += dot4(*(const float4*)&Am[j][4*k4], *(const float4*)&mun[4*k4]);
      muv[j] = m;
    }
    BAR();                                             // B7
  }
}

extern "C" void kernel_launch(void* const* d_in, const int* in_sizes, int n_in,
                              void* d_out, int out_size, void* d_ws, size_t ws_size,
                              hipStream_t stream) {
  const float* a    = (const float*)d_in[0];
  const float* A    = (const float*)d_in[1];
  const float* C    = (const float*)d_in[2];
  const float* a0   = (const float*)d_in[3];
  const float* Wih0 = (const float*)d_in[4];
  const float* Whh0 = (const float*)d_in[5];
  const float* bih0 = (const float*)d_in[6];
  const float* bhh0 = (const float*)d_in[7];
  const float* Wih1 = (const float*)d_in[8];
  const float* Whh1 = (const float*)d_in[9];
  const float* bih1 = (const float*)d_in[10];
  const float* bhh1 = (const float*)d_in[11];
  const float* Wlin = (const float*)d_in[12];
  const float* blin = (const float*)d_in[13];
  uint32_t* ws = (uint32_t*)d_ws;
  float* alpha = (float*)(ws + 103424);
  float* out = (float*)d_out;

  prep_kernel<<<404, 256, 0, stream>>>(Wih0, Whh0, bih0, bhh0, Wih1, Whh1, bih1, bhh1, ws);
  lstm_kernel<<<256, 512, 0, stream>>>(a, a0, ws, Wlin, blin, alpha);
  kalman_kernel<<<512, 256, 0, stream>>>(a, A, C, alpha, out);
}

// Round 5
// 1093.804 us; speedup vs baseline: 1.3923x; 1.3923x over previous
//
#include <hip/hip_runtime.h>
#include <hip/hip_fp16.h>
#include <cstdint>

#define T_LEN 128
#define DA    16
#define DZ    32
#define HH    128

__device__ __forceinline__ float sigm(float x){ return 1.0f/(1.0f + __expf(-x)); }
__device__ __forceinline__ float tanh_f(float x){ return 1.0f - 2.0f/(__expf(2.0f*x)+1.0f); }
__device__ __forceinline__ float dot4(float4 a, float4 b){ return a.x*b.x + a.y*b.y + a.z*b.z + a.w*b.w; }

typedef _Float16 h2v __attribute__((ext_vector_type(2)));
__device__ __forceinline__ float fdot2(uint32_t w, uint32_t h, float acc){
  union{uint32_t u; h2v v;} a, b; a.u = w; b.u = h;
  return __builtin_amdgcn_fdot2(a.v, b.v, acc, false);
}
__device__ __forceinline__ uint32_t packh2(float x, float y){
  return (uint32_t)__half_as_ushort(__float2half(x)) |
         ((uint32_t)__half_as_ushort(__float2half(y)) << 16);
}
__device__ __forceinline__ float h2lo(uint32_t u){
  return __half2float(__ushort_as_half((unsigned short)(u & 0xffffu)));
}
__device__ __forceinline__ float h2hi(uint32_t u){
  return __half2float(__ushort_as_half((unsigned short)(u >> 16)));
}
// dot of 8 fp16 (one uint4) against 8 fp16 (one uint4), fp32 accum
__device__ __forceinline__ float dot8(uint4 a, uint4 b, float acc){
  acc = fdot2(a.x, b.x, acc); acc = fdot2(a.y, b.y, acc);
  acc = fdot2(a.z, b.z, acc); acc = fdot2(a.w, b.w, acc);
  return acc;
}
// dot of 8 fp16 (uint4 h) against 8 fp32 (two float4), fp32 math
__device__ __forceinline__ float dot8f(uint4 h, float4 f0, float4 f1, float acc){
  acc += h2lo(h.x)*f0.x + h2hi(h.x)*f0.y + h2lo(h.y)*f0.z + h2hi(h.y)*f0.w;
  acc += h2lo(h.z)*f1.x + h2hi(h.z)*f1.y + h2lo(h.w)*f1.z + h2hi(h.w)*f1.w;
  return acc;
}

// LDS-only barrier: drain LDS pipe, raw s_barrier (no vmcnt drain).
#define BAR() do { asm volatile("s_waitcnt lgkmcnt(0)" ::: "memory"); \
                   __builtin_amdgcn_s_barrier(); } while (0)

__global__ void prep_kernel(const float* __restrict__ Wih0, const float* __restrict__ Whh0,
                            const float* __restrict__ bih0, const float* __restrict__ bhh0,
                            const float* __restrict__ Wih1, const float* __restrict__ Whh1,
                            const float* __restrict__ bih1, const float* __restrict__ bhh1,
                            uint32_t* __restrict__ ws) {
  int idx = blockIdx.x*256 + threadIdx.x;
  if (idx < 4096) {
    int q = idx & 3, g = (idx >> 2) & 511, m = idx >> 11;
    int k0 = 8*m + 2*q;
    ws[idx] = packh2(Wih0[g*DA + k0], Wih0[g*DA + k0 + 1]);
  } else if (idx < 36864) {
    int f = idx - 4096;
    int q = f & 3, g = (f >> 2) & 511, m = f >> 11;
    int k0 = 8*m + 2*q;
    ws[idx] = packh2(Whh0[g*HH + k0], Whh0[g*HH + k0 + 1]);
  } else if (idx < 69632) {
    int f = idx - 36864;
    int q = f & 3, g = (f >> 2) & 511, m = f >> 11;
    int k0 = 8*m + 2*q;
    ws[idx] = packh2(Wih1[g*HH + k0], Wih1[g*HH + k0 + 1]);
  } else if (idx < 102400) {
    int f = idx - 69632;
    int q = f & 3, g = (f >> 2) & 511, m = f >> 11;
    int k0 = 8*m + 2*q;
    ws[idx] = packh2(Whh1[g*HH + k0], Whh1[g*HH + k0 + 1]);
  } else if (idx < 102912) {
    int j = idx - 102400;
    ((float*)ws)[idx] = bih0[j] + bhh0[j];
  } else if (idx < 103424) {
    int j = idx - 102912;
    ((float*)ws)[idx] = bih1[j] + bhh1[j];
  }
}

// Persistent 2-layer LSTM (unchanged from round 4's fixed version).
__global__ __launch_bounds__(512, 2) void lstm_kernel(
    const float* __restrict__ a, const float* __restrict__ a0,
    const uint32_t* __restrict__ wsw, const float* __restrict__ Wlin,
    const float* __restrict__ blin, float* __restrict__ alpha_out) {
  const uint4* Wih0p = (const uint4*)(wsw);
  const uint4* Whh0p = (const uint4*)(wsw + 4096);
  const uint4* Wih1p = (const uint4*)(wsw + 36864);
  const uint4* Whh1p = (const uint4*)(wsw + 69632);
  const float* b0v = (const float*)(wsw + 102400);
  const float* b1v = (const float*)(wsw + 102912);

  __shared__ __align__(16) uint32_t sxh[2][T_LEN][8];
  __shared__ __align__(16) uint32_t sh0h[2][64];
  __shared__ __align__(16) uint32_t sh1h[2][64];
  __shared__ float gates[2][4*HH];

  int tid = threadIdx.x;
  int lane = tid & 63;
  int wv = tid >> 6;
  int bb = blockIdx.x * 2;

  uint4 wi0[2], wh0[16], wi1[16], wh1[16];
  #pragma unroll
  for (int m = 0; m < 2; ++m)  wi0[m] = Wih0p[m*512 + tid];
  #pragma unroll
  for (int m = 0; m < 16; ++m) wh0[m] = Whh0p[m*512 + tid];
  #pragma unroll
  for (int m = 0; m < 16; ++m) wi1[m] = Wih1p[m*512 + tid];
  #pragma unroll
  for (int m = 0; m < 16; ++m) wh1[m] = Whh1p[m*512 + tid];
  float bi0 = b0v[tid], bi1 = b1v[tid];

  for (int i = tid; i < 2*T_LEN*8; i += 512) {
    int r = i / (T_LEN*8), rem = i % (T_LEN*8), t = rem >> 3, p = rem & 7;
    float x0, x1;
    if (t == 0) { x0 = a0[2*p]; x1 = a0[2*p+1]; }
    else {
      const float* src = a + ((size_t)(bb + r)*T_LEN + (t-1))*DA;
      x0 = src[2*p]; x1 = src[2*p+1];
    }
    sxh[r][t][p] = packh2(x0, x1);
  }
  float wl00 = Wlin[0*HH + 2*lane], wl01 = Wlin[0*HH + 2*lane+1];
  float wl10 = Wlin[1*HH + 2*lane], wl11 = Wlin[1*HH + 2*lane+1];
  float wl20 = Wlin[2*HH + 2*lane], wl21 = Wlin[2*HH + 2*lane+1];
  float bl0 = blin[0], bl1 = blin[1], bl2 = blin[2];
  float c00 = 0.f, c01 = 0.f, c10 = 0.f, c11 = 0.f;
  if (tid < 128) { sh0h[wv][lane] = 0u; sh1h[wv][lane] = 0u; }
  __syncthreads();

  #pragma unroll 1
  for (int t = 0; t < T_LEN; ++t) {
    {
      float g0a = bi0, g0b = 0.f, g1a = bi0, g1b = 0.f;
      uint4 xA0 = *(const uint4*)&sxh[0][t][0];
      uint4 xA1 = *(const uint4*)&sxh[0][t][4];
      uint4 xB0 = *(const uint4*)&sxh[1][t][0];
      uint4 xB1 = *(const uint4*)&sxh[1][t][4];
      g0a = fdot2(wi0[0].x, xA0.x, g0a); g0b = fdot2(wi0[0].y, xA0.y, g0b);
      g0a = fdot2(wi0[0].z, xA0.z, g0a); g0b = fdot2(wi0[0].w, xA0.w, g0b);
      g0a = fdot2(wi0[1].x, xA1.x, g0a); g0b = fdot2(wi0[1].y, xA1.y, g0b);
      g0a = fdot2(wi0[1].z, xA1.z, g0a); g0b = fdot2(wi0[1].w, xA1.w, g0b);
      g1a = fdot2(wi0[0].x, xB0.x, g1a); g1b = fdot2(wi0[0].y, xB0.y, g1b);
      g1a = fdot2(wi0[0].z, xB0.z, g1a); g1b = fdot2(wi0[0].w, xB0.w, g1b);
      g1a = fdot2(wi0[1].x, xB1.x, g1a); g1b = fdot2(wi0[1].y, xB1.y, g1b);
      g1a = fdot2(wi0[1].z, xB1.z, g1a); g1b = fdot2(wi0[1].w, xB1.w, g1b);
      #pragma unroll
      for (int m = 0; m < 16; ++m) {
        uint4 w = wh0[m];
        uint4 hA = *(const uint4*)&sh0h[0][4*m];
        uint4 hB = *(const uint4*)&sh0h[1][4*m];
        g0a = fdot2(w.x, hA.x, g0a); g0b = fdot2(w.y, hA.y, g0b);
        g0a = fdot2(w.z, hA.z, g0a); g0b = fdot2(w.w, hA.w, g0b);
        g1a = fdot2(w.x, hB.x, g1a); g1b = fdot2(w.y, hB.y, g1b);
        g1a = fdot2(w.z, hB.z, g1a); g1b = fdot2(w.w, hB.w, g1b);
      }
      gates[0][tid] = g0a + g0b;
      gates[1][tid] = g1a + g1b;
    }
    __syncthreads();                                   // B1
    if (tid < 128) {
      int j0 = 2*lane, j1 = j0 + 1;
      float i0 = gates[wv][j0],      f0 = gates[wv][j0+HH],
            q0 = gates[wv][j0+2*HH], o0 = gates[wv][j0+3*HH];
      c00 = sigm(f0)*c00 + sigm(i0)*tanh_f(q0);
      float hv0 = sigm(o0)*tanh_f(c00);
      float i1 = gates[wv][j1],      f1 = gates[wv][j1+HH],
            q1 = gates[wv][j1+2*HH], o1 = gates[wv][j1+3*HH];
      c01 = sigm(f1)*c01 + sigm(i1)*tanh_f(q1);
      float hv1 = sigm(o1)*tanh_f(c01);
      sh0h[wv][lane] = packh2(hv0, hv1);
    }
    __syncthreads();                                   // B2
    {
      float g0a = bi1, g0b = 0.f, g1a = bi1, g1b = 0.f;
      #pragma unroll
      for (int m = 0; m < 16; ++m) {
        uint4 w = wi1[m];
        uint4 hA = *(const uint4*)&sh0h[0][4*m];
        uint4 hB = *(const uint4*)&sh0h[1][4*m];
        g0a = fdot2(w.x, hA.x, g0a); g0b = fdot2(w.y, hA.y, g0b);
        g0a = fdot2(w.z, hA.z, g0a); g0b = fdot2(w.w, hA.w, g0b);
        g1a = fdot2(w.x, hB.x, g1a); g1b = fdot2(w.y, hB.y, g1b);
        g1a = fdot2(w.z, hB.z, g1a); g1b = fdot2(w.w, hB.w, g1b);
      }
      #pragma unroll
      for (int m = 0; m < 16; ++m) {
        uint4 w = wh1[m];
        uint4 hA = *(const uint4*)&sh1h[0][4*m];
        uint4 hB = *(const uint4*)&sh1h[1][4*m];
        g0a = fdot2(w.x, hA.x, g0a); g0b = fdot2(w.y, hA.y, g0b);
        g0a = fdot2(w.z, hA.z, g0a); g0b = fdot2(w.w, hA.w, g0b);
        g1a = fdot2(w.x, hB.x, g1a); g1b = fdot2(w.y, hB.y, g1b);
        g1a = fdot2(w.z, hB.z, g1a); g1b = fdot2(w.w, hB.w, g1b);
      }
      gates[0][tid] = g0a + g0b;
      gates[1][tid] = g1a + g1b;
    }
    __syncthreads();                                   // B3
    float hv0 = 0.f, hv1 = 0.f;
    if (tid < 128) {
      int j0 = 2*lane, j1 = j0 + 1;
      float i0 = gates[wv][j0],      f0 = gates[wv][j0+HH],
            q0 = gates[wv][j0+2*HH], o0 = gates[wv][j0+3*HH];
      c10 = sigm(f0)*c10 + sigm(i0)*tanh_f(q0);
      hv0 = sigm(o0)*tanh_f(c10);
      float i1 = gates[wv][j1],      f1 = gates[wv][j1+HH],
            q1 = gates[wv][j1+2*HH], o1 = gates[wv][j1+3*HH];
      c11 = sigm(f1)*c11 + sigm(i1)*tanh_f(q1);
      hv1 = sigm(o1)*tanh_f(c11);
      sh1h[wv][lane] = packh2(hv0, hv1);
    }
    __syncthreads();                                   // B4
    if (tid < 128) {
      float p0 = hv0*wl00 + hv1*wl01;
      float p1 = hv0*wl10 + hv1*wl11;
      float p2 = hv0*wl20 + hv1*wl21;
      #pragma unroll
      for (int off = 32; off > 0; off >>= 1) {
        p0 += __shfl_down(p0, off); p1 += __shfl_down(p1, off); p2 += __shfl_down(p2, off);
      }
      if (lane == 0) {
        float l0 = p0 + bl0, l1 = p1 + bl1, l2 = p2 + bl2;
        float mx = fmaxf(l0, fmaxf(l1, l2));
        float e0=__expf(l0-mx), e1=__expf(l1-mx), e2=__expf(l2-mx);
        float inv = 1.0f/(e0+e1+e2);
        float* dst = alpha_out + (((size_t)(bb+wv))*T_LEN + t)*3;
        dst[0]=e0*inv; dst[1]=e1*inv; dst[2]=e2*inv;
      }
    }
  }
}

// Kalman scan v9: v4's wave-balanced all-256-thread structure, with every
// covariance matrix stored in LDS as packed fp16 (h2) and all mat-mat dots
// via v_dot2_f32_f16 (fp16 mul, fp32 accum). Rounds 1-4 showed the kernel is
// at the LDS return-bandwidth ceiling (~85 B/cyc) with 8 waves/CU; halving
// bytes+instructions via fp16 is the remaining lever. Row.row forms via
// symmetry of Sg/Sp2/Sinv keep packing k-adjacent everywhere. fp32 kept for:
// Gauss-Jordan, r, mu+, mu_pred, output. Row strides: 20 uint32 (80B, b128-
// aligned, 4-way on row-indexed reads) and 12 uint32 for 16-wide rows.
__global__ __launch_bounds__(256) void kalman_kernel(
    const float* __restrict__ a, const float* __restrict__ A,
    const float* __restrict__ C, const float* __restrict__ alpha,
    float* __restrict__ out) {
  __shared__ __align__(16) uint32_t SgH[DZ][20];   // Sigma_pred (h2)
  __shared__ __align__(16) uint32_t AmH[DZ][20];
  __shared__ __align__(16) uint32_t Sp2H[DZ][20];
  __shared__ __align__(16) uint32_t T2H[DZ][20];
  __shared__ __align__(16) uint32_t CmH[DA][20];
  __shared__ __align__(16) uint32_t NnTH[DA][20];  // (Sg Cm^T)^T rows (k-packed)
  __shared__ __align__(16) uint32_t NnH[DZ][12];   // Sg Cm^T rows (l-packed)
  __shared__ __align__(16) uint32_t KgH[DZ][12];
  __shared__ __align__(16) uint32_t SinvH[DA][12];
  __shared__ __align__(16) float Aug[DA][36];
  __shared__ __align__(16) float sa[T_LEN][DA];
  __shared__ float salpha[T_LEN*3];
  __shared__ __align__(16) float muvF[DZ], munF[DZ], rv[DA];

  int tid = threadIdx.x;
  int b = blockIdx.x;

  for (int e = tid; e < T_LEN*DA; e += 256) (&sa[0][0])[e] = a[(size_t)b*T_LEN*DA + e];
  for (int e = tid; e < T_LEN*3; e += 256) salpha[e] = alpha[(size_t)b*T_LEN*3 + e];
  __syncthreads();

  const int i8 = tid >> 3, jq = tid & 7;       // mix mapping (32 rows x 8 quads)
  const int i32 = tid & 31, g = tid >> 5;      // strip mappings (32 rows x 8 groups)
  const int j2 = g * 2, j4 = g * 4;

  // init: Sg = I (h2), mu = 0
  {
    uint2 iv;
    iv.x = packh2((i8==4*jq  )?1.f:0.f, (i8==4*jq+1)?1.f:0.f);
    iv.y = packh2((i8==4*jq+2)?1.f:0.f, (i8==4*jq+3)?1.f:0.f);
    *(uint2*)&SgH[i8][jq*2] = iv;
    if (tid < DZ) muvF[tid] = 0.0f;
  }

  const float4* A4 = (const float4*)A;
  const float4* C4 = (const float4*)C;
  float4 pA0 = A4[(0*T_LEN + 1)*256 + tid];
  float4 pA1 = A4[(1*T_LEN + 1)*256 + tid];
  float4 pA2 = A4[(2*T_LEN + 1)*256 + tid];
  float4 pC0, pC1, pC2;
  if (tid < 128) {
    pC0 = C4[(0*T_LEN + 0)*128 + tid];
    pC1 = C4[(1*T_LEN + 0)*128 + tid];
    pC2 = C4[(2*T_LEN + 0)*128 + tid];
  }
  __syncthreads();

  #pragma unroll 1
  for (int t = 0; t < T_LEN; ++t) {
    int ta = (t < T_LEN-1) ? t+1 : t;
    float b10 = salpha[ta*3+0], b11 = salpha[ta*3+1], b12 = salpha[ta*3+2];
    float b00 = salpha[t*3+0],  b01 = salpha[t*3+1],  b02 = salpha[t*3+2];

    // ---- mix: Am (alpha[ta]), Cm (alpha[t]) -> h2; issue next prefetch ----
    {
      float vx = b10*pA0.x + b11*pA1.x + b12*pA2.x;
      float vy = b10*pA0.y + b11*pA1.y + b12*pA2.y;
      float vz = b10*pA0.z + b11*pA1.z + b12*pA2.z;
      float vw = b10*pA0.w + b11*pA1.w + b12*pA2.w;
      uint2 pv; pv.x = packh2(vx, vy); pv.y = packh2(vz, vw);
      *(uint2*)&AmH[i8][jq*2] = pv;
      if (tid < 128) {
        float cx = b00*pC0.x + b01*pC1.x + b02*pC2.x;
        float cy = b00*pC0.y + b01*pC1.y + b02*pC2.y;
        float cz = b00*pC0.z + b01*pC1.z + b02*pC2.z;
        float cw = b00*pC0.w + b01*pC1.w + b02*pC2.w;
        uint2 pc; pc.x = packh2(cx, cy); pc.y = packh2(cz, cw);
        *(uint2*)&CmH[tid>>3][(tid&7)*2] = pc;
      }
      int tn  = (t+1 < T_LEN) ? t+1 : T_LEN-1;
      int tan = (tn < T_LEN-1) ? tn+1 : tn;
      pA0 = A4[(0*T_LEN + tan)*256 + tid];
      pA1 = A4[(1*T_LEN + tan)*256 + tid];
      pA2 = A4[(2*T_LEN + tan)*256 + tid];
      if (tid < 128) {
        pC0 = C4[(0*T_LEN + tn)*128 + tid];
        pC1 = C4[(1*T_LEN + tn)*128 + tid];
        pC2 = C4[(2*T_LEN + tn)*128 + tid];
      }
    }
    BAR();                                             // B0

    // ---- N[i][j] = dot(Sg_i, Cm_j) (strip2); also NnT scatter (b16) ----
    {
      uint4 s0 = *(const uint4*)&SgH[i32][0];
      uint4 s1 = *(const uint4*)&SgH[i32][4];
      uint4 s2 = *(const uint4*)&SgH[i32][8];
      uint4 s3 = *(const uint4*)&SgH[i32][12];
      uint4 cA0 = *(const uint4*)&CmH[j2][0];
      uint4 cA1 = *(const uint4*)&CmH[j2][4];
      uint4 cA2 = *(const uint4*)&CmH[j2][8];
      uint4 cA3 = *(const uint4*)&CmH[j2][12];
      uint4 cB0 = *(const uint4*)&CmH[j2+1][0];
      uint4 cB1 = *(const uint4*)&CmH[j2+1][4];
      uint4 cB2 = *(const uint4*)&CmH[j2+1][8];
      uint4 cB3 = *(const uint4*)&CmH[j2+1][12];
      float aA = dot8(s3,cA3, dot8(s2,cA2, dot8(s1,cA1, dot8(s0,cA0, 0.f))));
      float aB = dot8(s3,cB3, dot8(s2,cB2, dot8(s1,cB1, dot8(s0,cB0, 0.f))));
      NnH[i32][g] = packh2(aA, aB);
      __half* ntp = (__half*)&NnTH[0][0];
      ntp[j2*40 + i32]     = __float2half(aA);
      ntp[(j2+1)*40 + i32] = __float2half(aB);
    }
    BAR();                                             // B1

    // ---- Aug = [Cm*Sg*Cm^T + R | I]: S[i][j] = dot(Cm_i, NnT_j) ----
    {
      int i = tid & 15, j = tid >> 4;
      uint4 c0 = *(const uint4*)&CmH[i][0];
      uint4 c1 = *(const uint4*)&CmH[i][4];
      uint4 c2 = *(const uint4*)&CmH[i][8];
      uint4 c3 = *(const uint4*)&CmH[i][12];
      uint4 n0 = *(const uint4*)&NnTH[j][0];
      uint4 n1 = *(const uint4*)&NnTH[j][4];
      uint4 n2 = *(const uint4*)&NnTH[j][8];
      uint4 n3 = *(const uint4*)&NnTH[j][12];
      float s = dot8(c3,n3, dot8(c2,n2, dot8(c1,n1, dot8(c0,n0, 0.f))));
      Aug[i][j] = s + ((i == j) ? 0.01f : 0.0f);
      Aug[i][16 + j] = (i == j) ? 1.0f : 0.0f;
    }
    BAR();                                             // B2

    // ---- GJ (wave 0, fp32) -> Sinv h2; r (wave 1, fp32) ----
    if (tid < 64) {
      int lane = tid;
      int r = lane >> 2, cb = lane & 3;
      float v[8];
      #pragma unroll
      for (int j = 0; j < 8; ++j) v[j] = Aug[r][cb*8 + j];
      #define GJ_PIVOT(P, CTRL)                                                \
      {                                                                        \
        float App = __int_as_float(__builtin_amdgcn_readlane(                  \
                      __float_as_int(v[(P) & 7]), ((P) << 2) | ((P) >> 3)));   \
        float fv  = __int_as_float(__builtin_amdgcn_mov_dpp(                   \
                      __float_as_int(v[(P) & 7]), (CTRL), 0xf, 0xf, true));    \
        float prow[8];                                                         \
        _Pragma("unroll")                                                      \
        for (int j = 0; j < 8; ++j) prow[j] = __shfl(v[j], ((P) << 2) | cb, 64); \
        float pinv = 1.0f / App;                                               \
        if (r == (P)) {                                                        \
          _Pragma("unroll")                                                    \
          for (int j = 0; j < 8; ++j) v[j] *= pinv;                            \
        } else {                                                               \
          float fp = fv * pinv;                                                \
          _Pragma("unroll")                                                    \
          for (int j = 0; j < 8; ++j) v[j] -= fp * prow[j];                    \
        }                                                                      \
      }
      GJ_PIVOT(0, 0x00)  GJ_PIVOT(1, 0x00)  GJ_PIVOT(2, 0x00)  GJ_PIVOT(3, 0x00)
      GJ_PIVOT(4, 0x00)  GJ_PIVOT(5, 0x00)  GJ_PIVOT(6, 0x00)  GJ_PIVOT(7, 0x00)
      GJ_PIVOT(8, 0x55)  GJ_PIVOT(9, 0x55)  GJ_PIVOT(10, 0x55) GJ_PIVOT(11, 0x55)
      GJ_PIVOT(12, 0x55) GJ_PIVOT(13, 0x55) GJ_PIVOT(14, 0x55) GJ_PIVOT(15, 0x55)
      #undef GJ_PIVOT
      if (cb >= 2) {
        uint4 w;
        w.x = packh2(v[0], v[1]); w.y = packh2(v[2], v[3]);
        w.z = packh2(v[4], v[5]); w.w = packh2(v[6], v[7]);
        *(uint4*)&SinvH[r][(cb-2)*4] = w;
      }
    } else if (tid < 64 + DA) {
      int j = tid - 64;
      uint4 c0 = *(const uint4*)&CmH[j][0];
      uint4 c1 = *(const uint4*)&CmH[j][4];
      uint4 c2 = *(const uint4*)&CmH[j][8];
      uint4 c3 = *(const uint4*)&CmH[j][12];
      const float4* mv = (const float4*)muvF;
      float4 m0 = mv[0], m1 = mv[1], m2 = mv[2], m3 = mv[3];
      float4 m4 = mv[4], m5 = mv[5], m6 = mv[6], m7 = mv[7];
      float d = 0.f;
      d = dot8f(c0, m0, m1, d);
      d = dot8f(c1, m2, m3, d);
      d = dot8f(c2, m4, m5, d);
      d = dot8f(c3, m6, m7, d);
      rv[j] = sa[t][j] - d;
    }
    BAR();                                             // B3

    // ---- Kg[i][j] = dot(Nn_i, Sinv_j) (strip2; Sinv symmetric) ----
    {
      uint4 n0 = *(const uint4*)&NnH[i32][0];
      uint4 n1 = *(const uint4*)&NnH[i32][4];
      uint4 sA0 = *(const uint4*)&SinvH[j2][0];
      uint4 sA1 = *(const uint4*)&SinvH[j2][4];
      uint4 sB0 = *(const uint4*)&SinvH[j2+1][0];
      uint4 sB1 = *(const uint4*)&SinvH[j2+1][4];
      float aA = dot8(n1, sA1, dot8(n0, sA0, 0.f));
      float aB = dot8(n1, sB1, dot8(n0, sB0, 0.f));
      KgH[i32][g] = packh2(aA, aB);
    }
    BAR();                                             // B4

    // ---- Sp2[i][j] = Sg[i][j] - dot(Kg_i, Nn_j) (strip4); mu+ on wave 2 ----
    {
      uint4 k0 = *(const uint4*)&KgH[i32][0];
      uint4 k1 = *(const uint4*)&KgH[i32][4];
      float acc[4];
      #pragma unroll
      for (int c = 0; c < 4; ++c) {
        uint4 b0 = *(const uint4*)&NnH[j4+c][0];
        uint4 b1 = *(const uint4*)&NnH[j4+c][4];
        acc[c] = dot8(k1, b1, dot8(k0, b0, 0.f));
      }
      uint2 sgp = *(const uint2*)&SgH[i32][g*2];
      uint2 o;
      o.x = packh2(h2lo(sgp.x) - acc[0], h2hi(sgp.x) - acc[1]);
      o.y = packh2(h2lo(sgp.y) - acc[2], h2hi(sgp.y) - acc[3]);
      *(uint2*)&Sp2H[i32][g*2] = o;
    }
    if (tid >= 128 && tid < 128 + DZ) {
      int q = tid - 128;
      uint4 k0 = *(const uint4*)&KgH[q][0];
      uint4 k1 = *(const uint4*)&KgH[q][4];
      const float4* rp = (const float4*)rv;
      float4 r0 = rp[0], r1 = rp[1], r2 = rp[2], r3 = rp[3];
      float m = muvF[q];
      m = dot8f(k0, r0, r1, m);
      m = dot8f(k1, r2, r3, m);
      munF[q] = m;
      out[((size_t)b*T_LEN + t)*DZ + q] = m;
    }
    BAR();                                             // B5

    // ---- T2[i][j] = dot(Am_i, Sp2_j) (Sp2 symmetric; strip4) ----
    {
      uint4 a0 = *(const uint4*)&AmH[i32][0];
      uint4 a1 = *(const uint4*)&AmH[i32][4];
      uint4 a2 = *(const uint4*)&AmH[i32][8];
      uint4 a3 = *(const uint4*)&AmH[i32][12];
      float acc[4];
      #pragma unroll
      for (int c = 0; c < 4; ++c) {
        uint4 p0 = *(const uint4*)&Sp2H[j4+c][0];
        uint4 p1 = *(const uint4*)&Sp2H[j4+c][4];
        uint4 p2 = *(const uint4*)&Sp2H[j4+c][8];
        uint4 p3 = *(const uint4*)&Sp2H[j4+c][12];
        acc[c] = dot8(a3,p3, dot8(a2,p2, dot8(a1,p1, dot8(a0,p0, 0.f))));
      }
      uint2 o; o.x = packh2(acc[0], acc[1]); o.y = packh2(acc[2], acc[3]);
      *(uint2*)&T2H[i32][g*2] = o;
    }
    BAR();                                             // B6

    // ---- Sg'[i][j] = dot(T2_i, Am_j) + Q (strip4); mu_pred on wave 2 ----
    {
      uint4 t0 = *(const uint4*)&T2H[i32][0];
      uint4 t1 = *(const uint4*)&T2H[i32][4];
      uint4 t2 = *(const uint4*)&T2H[i32][8];
      uint4 t3 = *(const uint4*)&T2H[i32][12];
      float acc[4];
      #pragma unroll
      for (int c = 0; c < 4; ++c) {
        uint4 a0 = *(const uint4*)&AmH[j4+c][0];
        uint4 a1 = *(const uint4*)&AmH[j4+c][4];
        uint4 a2 = *(const uint4*)&AmH[j4+c][8];
        uint4 a3 = *(const uint4*)&AmH[j4+c][12];
        acc[c] = dot8(t3,a3, dot8(t2,a2, dot8(t1,a1, dot8(t0,a0, 0.f))));
        if (i32 == j4 + c) acc[c] += 0.01f;
      }
      uint2 o; o.x = packh2(acc[0], acc[1]); o.y = packh2(acc[2], acc[3]);
      *(uint2*)&SgH[i32][g*2] = o;
    }
    if (tid >= 128 && tid < 128 + DZ) {
      int q = tid - 128;
      uint4 a0 = *(const uint4*)&AmH[q][0];
      uint4 a1 = *(const uint4*)&AmH[q][4];
      uint4 a2 = *(const uint4*)&AmH[q][8];
      uint4 a3 = *(const uint4*)&AmH[q][12];
      const float4* mp = (const float4*)munF;
      float4 n0 = mp[0], n1 = mp[1], n2 = mp[2], n3 = mp[3];
      float4 n4 = mp[4], n5 = mp[5], n6 = mp[6], n7 = mp[7];
      float m = 0.f;
      m = dot8f(a0, n0, n1, m);
      m = dot8f(a1, n2, n3, m);
      m = dot8f(a2, n4, n5, m);
      m = dot8f(a3, n6, n7, m);
      muvF[q] = m;
    }
    BAR();                                             // B7
  }
}

extern "C" void kernel_launch(void* const* d_in, const int* in_sizes, int n_in,
                              void* d_out, int out_size, void* d_ws, size_t ws_size,
                              hipStream_t stream) {
  const float* a    = (const float*)d_in[0];
  const float* A    = (const float*)d_in[1];
  const float* C    = (const float*)d_in[2];
  const float* a0   = (const float*)d_in[3];
  const float* Wih0 = (const float*)d_in[4];
  const float* Whh0 = (const float*)d_in[5];
  const float* bih0 = (const float*)d_in[6];
  const float* bhh0 = (const float*)d_in[7];
  const float* Wih1 = (const float*)d_in[8];
  const float* Whh1 = (const float*)d_in[9];
  const float* bih1 = (const float*)d_in[10];
  const float* bhh1 = (const float*)d_in[11];
  const float* Wlin = (const float*)d_in[12];
  const float* blin = (const float*)d_in[13];
  uint32_t* ws = (uint32_t*)d_ws;
  float* alpha = (float*)(ws + 103424);
  float* out = (float*)d_out;

  prep_kernel<<<404, 256, 0, stream>>>(Wih0, Whh0, bih0, bhh0, Wih1, Whh1, bih1, bhh1, ws);
  lstm_kernel<<<256, 512, 0, stream>>>(a, a0, ws, Wlin, blin, alpha);
  kalman_kernel<<<512, 256, 0, stream>>>(a, A, C, alpha, out);
}

// Round 7
// 1068.381 us; speedup vs baseline: 1.4255x; 1.0238x over previous
//
#include <hip/hip_runtime.h>
#include <hip/hip_fp16.h>
#include <cstdint>

#define T_LEN 128
#define DA    16
#define DZ    32
#define HH    128

__device__ __forceinline__ float sigm(float x){ return 1.0f/(1.0f + __expf(-x)); }
__device__ __forceinline__ float tanh_f(float x){ return 1.0f - 2.0f/(__expf(2.0f*x)+1.0f); }
__device__ __forceinline__ float dot4(float4 a, float4 b){ return a.x*b.x + a.y*b.y + a.z*b.z + a.w*b.w; }

typedef _Float16 h2v __attribute__((ext_vector_type(2)));
__device__ __forceinline__ float fdot2(uint32_t w, uint32_t h, float acc){
  union{uint32_t u; h2v v;} a, b; a.u = w; b.u = h;
  return __builtin_amdgcn_fdot2(a.v, b.v, acc, false);
}
__device__ __forceinline__ uint32_t packh2(float x, float y){
  return (uint32_t)__half_as_ushort(__float2half(x)) |
         ((uint32_t)__half_as_ushort(__float2half(y)) << 16);
}
__device__ __forceinline__ float h2lo(uint32_t u){
  return __half2float(__ushort_as_half((unsigned short)(u & 0xffffu)));
}
__device__ __forceinline__ float h2hi(uint32_t u){
  return __half2float(__ushort_as_half((unsigned short)(u >> 16)));
}
// dot of 8 fp16 (one uint4) against 8 fp16 (one uint4), fp32 accum
__device__ __forceinline__ float dot8(uint4 a, uint4 b, float acc){
  acc = fdot2(a.x, b.x, acc); acc = fdot2(a.y, b.y, acc);
  acc = fdot2(a.z, b.z, acc); acc = fdot2(a.w, b.w, acc);
  return acc;
}
// dot of 8 fp16 (uint4 h) against 8 fp32 (two float4), fp32 math
__device__ __forceinline__ float dot8f(uint4 h, float4 f0, float4 f1, float acc){
  acc += h2lo(h.x)*f0.x + h2hi(h.x)*f0.y + h2lo(h.y)*f0.z + h2hi(h.y)*f0.w;
  acc += h2lo(h.z)*f1.x + h2hi(h.z)*f1.y + h2lo(h.w)*f1.z + h2hi(h.w)*f1.w;
  return acc;
}

// LDS-only barrier: drain LDS pipe, raw s_barrier (no vmcnt drain).
#define BAR() do { asm volatile("s_waitcnt lgkmcnt(0)" ::: "memory"); \
                   __builtin_amdgcn_s_barrier(); } while (0)

__global__ void prep_kernel(const float* __restrict__ Wih0, const float* __restrict__ Whh0,
                            const float* __restrict__ bih0, const float* __restrict__ bhh0,
                            const float* __restrict__ Wih1, const float* __restrict__ Whh1,
                            const float* __restrict__ bih1, const float* __restrict__ bhh1,
                            uint32_t* __restrict__ ws) {
  int idx = blockIdx.x*256 + threadIdx.x;
  if (idx < 4096) {
    int q = idx & 3, g = (idx >> 2) & 511, m = idx >> 11;
    int k0 = 8*m + 2*q;
    ws[idx] = packh2(Wih0[g*DA + k0], Wih0[g*DA + k0 + 1]);
  } else if (idx < 36864) {
    int f = idx - 4096;
    int q = f & 3, g = (f >> 2) & 511, m = f >> 11;
    int k0 = 8*m + 2*q;
    ws[idx] = packh2(Whh0[g*HH + k0], Whh0[g*HH + k0 + 1]);
  } else if (idx < 69632) {
    int f = idx - 36864;
    int q = f & 3, g = (f >> 2) & 511, m = f >> 11;
    int k0 = 8*m + 2*q;
    ws[idx] = packh2(Wih1[g*HH + k0], Wih1[g*HH + k0 + 1]);
  } else if (idx < 102400) {
    int f = idx - 69632;
    int q = f & 3, g = (f >> 2) & 511, m = f >> 11;
    int k0 = 8*m + 2*q;
    ws[idx] = packh2(Whh1[g*HH + k0], Whh1[g*HH + k0 + 1]);
  } else if (idx < 102912) {
    int j = idx - 102400;
    ((float*)ws)[idx] = bih0[j] + bhh0[j];
  } else if (idx < 103424) {
    int j = idx - 102912;
    ((float*)ws)[idx] = bih1[j] + bhh1[j];
  }
}

// Persistent 2-layer LSTM: round-6 variant (4-wave activations, fp16 h store,
// head reads h from LDS). Kept for the bisect.
__global__ __launch_bounds__(512, 2) void lstm_kernel(
    const float* __restrict__ a, const float* __restrict__ a0,
    const uint32_t* __restrict__ wsw, const float* __restrict__ Wlin,
    const float* __restrict__ blin, float* __restrict__ alpha_out) {
  const uint4* Wih0p = (const uint4*)(wsw);
  const uint4* Whh0p = (const uint4*)(wsw + 4096);
  const uint4* Wih1p = (const uint4*)(wsw + 36864);
  const uint4* Whh1p = (const uint4*)(wsw + 69632);
  const float* b0v = (const float*)(wsw + 102400);
  const float* b1v = (const float*)(wsw + 102912);

  __shared__ __align__(16) uint32_t sxh[2][T_LEN][8];
  __shared__ __align__(16) uint32_t sh0h[2][64];
  __shared__ __align__(16) uint32_t sh1h[2][64];
  __shared__ float gates[2][4*HH];

  int tid = threadIdx.x;
  int lane = tid & 63;
  int wv = tid >> 6;
  int bb = blockIdx.x * 2;

  uint4 wi0[2], wh0[16], wi1[16], wh1[16];
  #pragma unroll
  for (int m = 0; m < 2; ++m)  wi0[m] = Wih0p[m*512 + tid];
  #pragma unroll
  for (int m = 0; m < 16; ++m) wh0[m] = Whh0p[m*512 + tid];
  #pragma unroll
  for (int m = 0; m < 16; ++m) wi1[m] = Wih1p[m*512 + tid];
  #pragma unroll
  for (int m = 0; m < 16; ++m) wh1[m] = Whh1p[m*512 + tid];
  float bi0 = b0v[tid], bi1 = b1v[tid];

  for (int i = tid; i < 2*T_LEN*8; i += 512) {
    int r = i / (T_LEN*8), rem = i % (T_LEN*8), t = rem >> 3, p = rem & 7;
    float x0, x1;
    if (t == 0) { x0 = a0[2*p]; x1 = a0[2*p+1]; }
    else {
      const float* src = a + ((size_t)(bb + r)*T_LEN + (t-1))*DA;
      x0 = src[2*p]; x1 = src[2*p+1];
    }
    sxh[r][t][p] = packh2(x0, x1);
  }
  float wl00 = Wlin[0*HH + 2*lane], wl01 = Wlin[0*HH + 2*lane+1];
  float wl10 = Wlin[1*HH + 2*lane], wl11 = Wlin[1*HH + 2*lane+1];
  float wl20 = Wlin[2*HH + 2*lane], wl21 = Wlin[2*HH + 2*lane+1];
  float bl0 = blin[0], bl1 = blin[1], bl2 = blin[2];
  // cell states: thread < 256 owns (row = tid>>7, cell = tid&127) in both layers
  float cl0 = 0.f, cl1 = 0.f;
  if (tid < 128) { sh0h[wv][lane] = 0u; sh1h[wv][lane] = 0u; }
  __syncthreads();

  #pragma unroll 1
  for (int t = 0; t < T_LEN; ++t) {
    {
      float g0a = bi0, g0b = 0.f, g1a = bi0, g1b = 0.f;
      uint4 xA0 = *(const uint4*)&sxh[0][t][0];
      uint4 xA1 = *(const uint4*)&sxh[0][t][4];
      uint4 xB0 = *(const uint4*)&sxh[1][t][0];
      uint4 xB1 = *(const uint4*)&sxh[1][t][4];
      g0a = fdot2(wi0[0].x, xA0.x, g0a); g0b = fdot2(wi0[0].y, xA0.y, g0b);
      g0a = fdot2(wi0[0].z, xA0.z, g0a); g0b = fdot2(wi0[0].w, xA0.w, g0b);
      g0a = fdot2(wi0[1].x, xA1.x, g0a); g0b = fdot2(wi0[1].y, xA1.y, g0b);
      g0a = fdot2(wi0[1].z, xA1.z, g0a); g0b = fdot2(wi0[1].w, xA1.w, g0b);
      g1a = fdot2(wi0[0].x, xB0.x, g1a); g1b = fdot2(wi0[0].y, xB0.y, g1b);
      g1a = fdot2(wi0[0].z, xB0.z, g1a); g1b = fdot2(wi0[0].w, xB0.w, g1b);
      g1a = fdot2(wi0[1].x, xB1.x, g1a); g1b = fdot2(wi0[1].y, xB1.y, g1b);
      g1a = fdot2(wi0[1].z, xB1.z, g1a); g1b = fdot2(wi0[1].w, xB1.w, g1b);
      #pragma unroll
      for (int m = 0; m < 16; ++m) {
        uint4 w = wh0[m];
        uint4 hA = *(const uint4*)&sh0h[0][4*m];
        uint4 hB = *(const uint4*)&sh0h[1][4*m];
        g0a = fdot2(w.x, hA.x, g0a); g0b = fdot2(w.y, hA.y, g0b);
        g0a = fdot2(w.z, hA.z, g0a); g0b = fdot2(w.w, hA.w, g0b);
        g1a = fdot2(w.x, hB.x, g1a); g1b = fdot2(w.y, hB.y, g1b);
        g1a = fdot2(w.z, hB.z, g1a); g1b = fdot2(w.w, hB.w, g1b);
      }
      gates[0][tid] = g0a + g0b;
      gates[1][tid] = g1a + g1b;
    }
    __syncthreads();                                   // B1
    if (tid < 256) {
      int row = tid >> 7, cell = tid & 127;
      float iv = gates[row][cell],      fv = gates[row][cell+HH],
            qv = gates[row][cell+2*HH], ov = gates[row][cell+3*HH];
      cl0 = sigm(fv)*cl0 + sigm(iv)*tanh_f(qv);
      float hv = sigm(ov)*tanh_f(cl0);
      ((__half*)&sh0h[0][0])[row*128 + cell] = __float2half(hv);
    }
    __syncthreads();                                   // B2
    {
      float g0a = bi1, g0b = 0.f, g1a = bi1, g1b = 0.f;
      #pragma unroll
      for (int m = 0; m < 16; ++m) {
        uint4 w = wi1[m];
        uint4 hA = *(const uint4*)&sh0h[0][4*m];
        uint4 hB = *(const uint4*)&sh0h[1][4*m];
        g0a = fdot2(w.x, hA.x, g0a); g0b = fdot2(w.y, hA.y, g0b);
        g0a = fdot2(w.z, hA.z, g0a); g0b = fdot2(w.w, hA.w, g0b);
        g1a = fdot2(w.x, hB.x, g1a); g1b = fdot2(w.y, hB.y, g1b);
        g1a = fdot2(w.z, hB.z, g1a); g1b = fdot2(w.w, hB.w, g1b);
      }
      #pragma unroll
      for (int m = 0; m < 16; ++m) {
        uint4 w = wh1[m];
        uint4 hA = *(const uint4*)&sh1h[0][4*m];
        uint4 hB = *(const uint4*)&sh1h[1][4*m];
        g0a = fdot2(w.x, hA.x, g0a); g0b = fdot2(w.y, hA.y, g0b);
        g0a = fdot2(w.z, hA.z, g0a); g0b = fdot2(w.w, hA.w, g0b);
        g1a = fdot2(w.x, hB.x, g1a); g1b = fdot2(w.y, hB.y, g1b);
        g1a = fdot2(w.z, hB.z, g1a); g1b = fdot2(w.w, hB.w, g1b);
      }
      gates[0][tid] = g0a + g0b;
      gates[1][tid] = g1a + g1b;
    }
    __syncthreads();                                   // B3
    if (tid < 256) {
      int row = tid >> 7, cell = tid & 127;
      float iv = gates[row][cell],      fv = gates[row][cell+HH],
            qv = gates[row][cell+2*HH], ov = gates[row][cell+3*HH];
      cl1 = sigm(fv)*cl1 + sigm(iv)*tanh_f(qv);
      float hv = sigm(ov)*tanh_f(cl1);
      ((__half*)&sh1h[0][0])[row*128 + cell] = __float2half(hv);
    }
    __syncthreads();                                   // B4
    if (tid < 128) {
      uint32_t hw = sh1h[wv][lane];
      float hv0 = h2lo(hw), hv1 = h2hi(hw);
      float p0 = hv0*wl00 + hv1*wl01;
      float p1 = hv0*wl10 + hv1*wl11;
      float p2 = hv0*wl20 + hv1*wl21;
      #pragma unroll
      for (int off = 32; off > 0; off >>= 1) {
        p0 += __shfl_down(p0, off); p1 += __shfl_down(p1, off); p2 += __shfl_down(p2, off);
      }
      if (lane == 0) {
        float l0 = p0 + bl0, l1 = p1 + bl1, l2 = p2 + bl2;
        float mx = fmaxf(l0, fmaxf(l1, l2));
        float e0=__expf(l0-mx), e1=__expf(l1-mx), e2=__expf(l2-mx);
        float inv = 1.0f/(e0+e1+e2);
        float* dst = alpha_out + (((size_t)(bb+wv))*T_LEN + t)*3;
        dst[0]=e0*inv; dst[1]=e1*inv; dst[2]=e2*inv;
      }
    }
  }
}

// Kalman scan: EXACT round-5 v9 (known-pass, 655us, absmax 0.133). The v10
// phase-merge produced NaN; this round bisects (new LSTM + proven kalman).
__global__ __launch_bounds__(256) void kalman_kernel(
    const float* __restrict__ a, const float* __restrict__ A,
    const float* __restrict__ C, const float* __restrict__ alpha,
    float* __restrict__ out) {
  __shared__ __align__(16) uint32_t SgH[DZ][20];   // Sigma_pred (h2)
  __shared__ __align__(16) uint32_t AmH[DZ][20];
  __shared__ __align__(16) uint32_t Sp2H[DZ][20];
  __shared__ __align__(16) uint32_t T2H[DZ][20];
  __shared__ __align__(16) uint32_t CmH[DA][20];
  __shared__ __align__(16) uint32_t NnTH[DA][20];  // (Sg Cm^T)^T rows (k-packed)
  __shared__ __align__(16) uint32_t NnH[DZ][12];   // Sg Cm^T rows (l-packed)
  __shared__ __align__(16) uint32_t KgH[DZ][12];
  __shared__ __align__(16) uint32_t SinvH[DA][12];
  __shared__ __align__(16) float Aug[DA][36];
  __shared__ __align__(16) float sa[T_LEN][DA];
  __shared__ float salpha[T_LEN*3];
  __shared__ __align__(16) float muvF[DZ], munF[DZ], rv[DA];

  int tid = threadIdx.x;
  int b = blockIdx.x;

  for (int e = tid; e < T_LEN*DA; e += 256) (&sa[0][0])[e] = a[(size_t)b*T_LEN*DA + e];
  for (int e = tid; e < T_LEN*3; e += 256) salpha[e] = alpha[(size_t)b*T_LEN*3 + e];
  __syncthreads();

  const int i8 = tid >> 3, jq = tid & 7;       // mix mapping (32 rows x 8 quads)
  const int i32 = tid & 31, g = tid >> 5;      // strip mappings (32 rows x 8 groups)
  const int j2 = g * 2, j4 = g * 4;

  // init: Sg = I (h2), mu = 0
  {
    uint2 iv;
    iv.x = packh2((i8==4*jq  )?1.f:0.f, (i8==4*jq+1)?1.f:0.f);
    iv.y = packh2((i8==4*jq+2)?1.f:0.f, (i8==4*jq+3)?1.f:0.f);
    *(uint2*)&SgH[i8][jq*2] = iv;
    if (tid < DZ) muvF[tid] = 0.0f;
  }

  const float4* A4 = (const float4*)A;
  const float4* C4 = (const float4*)C;
  float4 pA0 = A4[(0*T_LEN + 1)*256 + tid];
  float4 pA1 = A4[(1*T_LEN + 1)*256 + tid];
  float4 pA2 = A4[(2*T_LEN + 1)*256 + tid];
  float4 pC0, pC1, pC2;
  if (tid < 128) {
    pC0 = C4[(0*T_LEN + 0)*128 + tid];
    pC1 = C4[(1*T_LEN + 0)*128 + tid];
    pC2 = C4[(2*T_LEN + 0)*128 + tid];
  }
  __syncthreads();

  #pragma unroll 1
  for (int t = 0; t < T_LEN; ++t) {
    int ta = (t < T_LEN-1) ? t+1 : t;
    float b10 = salpha[ta*3+0], b11 = salpha[ta*3+1], b12 = salpha[ta*3+2];
    float b00 = salpha[t*3+0],  b01 = salpha[t*3+1],  b02 = salpha[t*3+2];

    // ---- mix: Am (alpha[ta]), Cm (alpha[t]) -> h2; issue next prefetch ----
    {
      float vx = b10*pA0.x + b11*pA1.x + b12*pA2.x;
      float vy = b10*pA0.y + b11*pA1.y + b12*pA2.y;
      float vz = b10*pA0.z + b11*pA1.z + b12*pA2.z;
      float vw = b10*pA0.w + b11*pA1.w + b12*pA2.w;
      uint2 pv; pv.x = packh2(vx, vy); pv.y = packh2(vz, vw);
      *(uint2*)&AmH[i8][jq*2] = pv;
      if (tid < 128) {
        float cx = b00*pC0.x + b01*pC1.x + b02*pC2.x;
        float cy = b00*pC0.y + b01*pC1.y + b02*pC2.y;
        float cz = b00*pC0.z + b01*pC1.z + b02*pC2.z;
        float cw = b00*pC0.w + b01*pC1.w + b02*pC2.w;
        uint2 pc; pc.x = packh2(cx, cy); pc.y = packh2(cz, cw);
        *(uint2*)&CmH[tid>>3][(tid&7)*2] = pc;
      }
      int tn  = (t+1 < T_LEN) ? t+1 : T_LEN-1;
      int tan = (tn < T_LEN-1) ? tn+1 : tn;
      pA0 = A4[(0*T_LEN + tan)*256 + tid];
      pA1 = A4[(1*T_LEN + tan)*256 + tid];
      pA2 = A4[(2*T_LEN + tan)*256 + tid];
      if (tid < 128) {
        pC0 = C4[(0*T_LEN + tn)*128 + tid];
        pC1 = C4[(1*T_LEN + tn)*128 + tid];
        pC2 = C4[(2*T_LEN + tn)*128 + tid];
      }
    }
    BAR();                                             // B0

    // ---- N[i][j] = dot(Sg_i, Cm_j) (strip2); also NnT scatter (b16) ----
    {
      uint4 s0 = *(const uint4*)&SgH[i32][0];
      uint4 s1 = *(const uint4*)&SgH[i32][4];
      uint4 s2 = *(const uint4*)&SgH[i32][8];
      uint4 s3 = *(const uint4*)&SgH[i32][12];
      uint4 cA0 = *(const uint4*)&CmH[j2][0];
      uint4 cA1 = *(const uint4*)&CmH[j2][4];
      uint4 cA2 = *(const uint4*)&CmH[j2][8];
      uint4 cA3 = *(const uint4*)&CmH[j2][12];
      uint4 cB0 = *(const uint4*)&CmH[j2+1][0];
      uint4 cB1 = *(const uint4*)&CmH[j2+1][4];
      uint4 cB2 = *(const uint4*)&CmH[j2+1][8];
      uint4 cB3 = *(const uint4*)&CmH[j2+1][12];
      float aA = dot8(s3,cA3, dot8(s2,cA2, dot8(s1,cA1, dot8(s0,cA0, 0.f))));
      float aB = dot8(s3,cB3, dot8(s2,cB2, dot8(s1,cB1, dot8(s0,cB0, 0.f))));
      NnH[i32][g] = packh2(aA, aB);
      __half* ntp = (__half*)&NnTH[0][0];
      ntp[j2*40 + i32]     = __float2half(aA);
      ntp[(j2+1)*40 + i32] = __float2half(aB);
    }
    BAR();                                             // B1

    // ---- Aug = [Cm*Sg*Cm^T + R | I]: S[i][j] = dot(Cm_i, NnT_j) ----
    {
      int i = tid & 15, j = tid >> 4;
      uint4 c0 = *(const uint4*)&CmH[i][0];
      uint4 c1 = *(const uint4*)&CmH[i][4];
      uint4 c2 = *(const uint4*)&CmH[i][8];
      uint4 c3 = *(const uint4*)&CmH[i][12];
      uint4 n0 = *(const uint4*)&NnTH[j][0];
      uint4 n1 = *(const uint4*)&NnTH[j][4];
      uint4 n2 = *(const uint4*)&NnTH[j][8];
      uint4 n3 = *(const uint4*)&NnTH[j][12];
      float s = dot8(c3,n3, dot8(c2,n2, dot8(c1,n1, dot8(c0,n0, 0.f))));
      Aug[i][j] = s + ((i == j) ? 0.01f : 0.0f);
      Aug[i][16 + j] = (i == j) ? 1.0f : 0.0f;
    }
    BAR();                                             // B2

    // ---- GJ (wave 0, fp32) -> Sinv h2; r (wave 1, fp32) ----
    if (tid < 64) {
      int lane = tid;
      int r = lane >> 2, cb = lane & 3;
      float v[8];
      #pragma unroll
      for (int j = 0; j < 8; ++j) v[j] = Aug[r][cb*8 + j];
      #define GJ_PIVOT(P, CTRL)                                                \
      {                                                                        \
        float App = __int_as_float(__builtin_amdgcn_readlane(                  \
                      __float_as_int(v[(P) & 7]), ((P) << 2) | ((P) >> 3)));   \
        float fv  = __int_as_float(__builtin_amdgcn_mov_dpp(                   \
                      __float_as_int(v[(P) & 7]), (CTRL), 0xf, 0xf, true));    \
        float prow[8];                                                         \
        _Pragma("unroll")                                                      \
        for (int j = 0; j < 8; ++j) prow[j] = __shfl(v[j], ((P) << 2) | cb, 64); \
        float pinv = 1.0f / App;                                               \
        if (r == (P)) {                                                        \
          _Pragma("unroll")                                                    \
          for (int j = 0; j < 8; ++j) v[j] *= pinv;                            \
        } else {                                                               \
          float fp = fv * pinv;                                                \
          _Pragma("unroll")                                                    \
          for (int j = 0; j < 8; ++j) v[j] -= fp * prow[j];                    \
        }                                                                      \
      }
      GJ_PIVOT(0, 0x00)  GJ_PIVOT(1, 0x00)  GJ_PIVOT(2, 0x00)  GJ_PIVOT(3, 0x00)
      GJ_PIVOT(4, 0x00)  GJ_PIVOT(5, 0x00)  GJ_PIVOT(6, 0x00)  GJ_PIVOT(7, 0x00)
      GJ_PIVOT(8, 0x55)  GJ_PIVOT(9, 0x55)  GJ_PIVOT(10, 0x55) GJ_PIVOT(11, 0x55)
      GJ_PIVOT(12, 0x55) GJ_PIVOT(13, 0x55) GJ_PIVOT(14, 0x55) GJ_PIVOT(15, 0x55)
      #undef GJ_PIVOT
      if (cb >= 2) {
        uint4 w;
        w.x = packh2(v[0], v[1]); w.y = packh2(v[2], v[3]);
        w.z = packh2(v[4], v[5]); w.w = packh2(v[6], v[7]);
        *(uint4*)&SinvH[r][(cb-2)*4] = w;
      }
    } else if (tid < 64 + DA) {
      int j = tid - 64;
      uint4 c0 = *(const uint4*)&CmH[j][0];
      uint4 c1 = *(const uint4*)&CmH[j][4];
      uint4 c2 = *(const uint4*)&CmH[j][8];
      uint4 c3 = *(const uint4*)&CmH[j][12];
      const float4* mv = (const float4*)muvF;
      float4 m0 = mv[0], m1 = mv[1], m2 = mv[2], m3 = mv[3];
      float4 m4 = mv[4], m5 = mv[5], m6 = mv[6], m7 = mv[7];
      float d = 0.f;
      d = dot8f(c0, m0, m1, d);
      d = dot8f(c1, m2, m3, d);
      d = dot8f(c2, m4, m5, d);
      d = dot8f(c3, m6, m7, d);
      rv[j] = sa[t][j] - d;
    }
    BAR();                                             // B3

    // ---- Kg[i][j] = dot(Nn_i, Sinv_j) (strip2; Sinv symmetric) ----
    {
      uint4 n0 = *(const uint4*)&NnH[i32][0];
      uint4 n1 = *(const uint4*)&NnH[i32][4];
      uint4 sA0 = *(const uint4*)&SinvH[j2][0];
      uint4 sA1 = *(const uint4*)&SinvH[j2][4];
      uint4 sB0 = *(const uint4*)&SinvH[j2+1][0];
      uint4 sB1 = *(const uint4*)&SinvH[j2+1][4];
      float aA = dot8(n1, sA1, dot8(n0, sA0, 0.f));
      float aB = dot8(n1, sB1, dot8(n0, sB0, 0.f));
      KgH[i32][g] = packh2(aA, aB);
    }
    BAR();                                             // B4

    // ---- Sp2[i][j] = Sg[i][j] - dot(Kg_i, Nn_j) (strip4); mu+ on wave 2 ----
    {
      uint4 k0 = *(const uint4*)&KgH[i32][0];
      uint4 k1 = *(const uint4*)&KgH[i32][4];
      float acc[4];
      #pragma unroll
      for (int c = 0; c < 4; ++c) {
        uint4 b0 = *(const uint4*)&NnH[j4+c][0];
        uint4 b1 = *(const uint4*)&NnH[j4+c][4];
        acc[c] = dot8(k1, b1, dot8(k0, b0, 0.f));
      }
      uint2 sgp = *(const uint2*)&SgH[i32][g*2];
      uint2 o;
      o.x = packh2(h2lo(sgp.x) - acc[0], h2hi(sgp.x) - acc[1]);
      o.y = packh2(h2lo(sgp.y) - acc[2], h2hi(sgp.y) - acc[3]);
      *(uint2*)&Sp2H[i32][g*2] = o;
    }
    if (tid >= 128 && tid < 128 + DZ) {
      int q = tid - 128;
      uint4 k0 = *(const uint4*)&KgH[q][0];
      uint4 k1 = *(const uint4*)&KgH[q][4];
      const float4* rp = (const float4*)rv;
      float4 r0 = rp[0], r1 = rp[1], r2 = rp[2], r3 = rp[3];
      float m = muvF[q];
      m = dot8f(k0, r0, r1, m);
      m = dot8f(k1, r2, r3, m);
      munF[q] = m;
      out[((size_t)b*T_LEN + t)*DZ + q] = m;
    }
    BAR();                                             // B5

    // ---- T2[i][j] = dot(Am_i, Sp2_j) (Sp2 symmetric; strip4) ----
    {
      uint4 a0 = *(const uint4*)&AmH[i32][0];
      uint4 a1 = *(const uint4*)&AmH[i32][4];
      uint4 a2 = *(const uint4*)&AmH[i32][8];
      uint4 a3 = *(const uint4*)&AmH[i32][12];
      float acc[4];
      #pragma unroll
      for (int c = 0; c < 4; ++c) {
        uint4 p0 = *(const uint4*)&Sp2H[j4+c][0];
        uint4 p1 = *(const uint4*)&Sp2H[j4+c][4];
        uint4 p2 = *(const uint4*)&Sp2H[j4+c][8];
        uint4 p3 = *(const uint4*)&Sp2H[j4+c][12];
        acc[c] = dot8(a3,p3, dot8(a2,p2, dot8(a1,p1, dot8(a0,p0, 0.f))));
      }
      uint2 o; o.x = packh2(acc[0], acc[1]); o.y = packh2(acc[2], acc[3]);
      *(uint2*)&T2H[i32][g*2] = o;
    }
    BAR();                                             // B6

    // ---- Sg'[i][j] = dot(T2_i, Am_j) + Q (strip4); mu_pred on wave 2 ----
    {
      uint4 t0 = *(const uint4*)&T2H[i32][0];
      uint4 t1 = *(const uint4*)&T2H[i32][4];
      uint4 t2 = *(const uint4*)&T2H[i32][8];
      uint4 t3 = *(const uint4*)&T2H[i32][12];
      float acc[4];
      #pragma unroll
      for (int c = 0; c < 4; ++c) {
        uint4 a0 = *(const uint4*)&AmH[j4+c][0];
        uint4 a1 = *(const uint4*)&AmH[j4+c][4];
        uint4 a2 = *(const uint4*)&AmH[j4+c][8];
        uint4 a3 = *(const uint4*)&AmH[j4+c][12];
        acc[c] = dot8(t3,a3, dot8(t2,a2, dot8(t1,a1, dot8(t0,a0, 0.f))));
        if (i32 == j4 + c) acc[c] += 0.01f;
      }
      uint2 o; o.x = packh2(acc[0], acc[1]); o.y = packh2(acc[2], acc[3]);
      *(uint2*)&SgH[i32][g*2] = o;
    }
    if (tid >= 128 && tid < 128 + DZ) {
      int q = tid - 128;
      uint4 a0 = *(const uint4*)&AmH[q][0];
      uint4 a1 = *(const uint4*)&AmH[q][4];
      uint4 a2 = *(const uint4*)&AmH[q][8];
      uint4 a3 = *(const uint4*)&AmH[q][12];
      const float4* mp = (const float4*)munF;
      float4 n0 = mp[0], n1 = mp[1], n2 = mp[2], n3 = mp[3];
      float4 n4 = mp[4], n5 = mp[5], n6 = mp[6], n7 = mp[7];
      float m = 0.f;
      m = dot8f(a0, n0, n1, m);
      m = dot8f(a1, n2, n3, m);
      m = dot8f(a2, n4, n5, m);
      m = dot8f(a3, n6, n7, m);
      muvF[q] = m;
    }
    BAR();                                             // B7
  }
}

extern "C" void kernel_launch(void* const* d_in, const int* in_sizes, int n_in,
                              void* d_out, int out_size, void* d_ws, size_t ws_size,
                              hipStream_t stream) {
  const float* a    = (const float*)d_in[0];
  const float* A    = (const float*)d_in[1];
  const float* C    = (const float*)d_in[2];
  const float* a0   = (const float*)d_in[3];
  const float* Wih0 = (const float*)d_in[4];
  const float* Whh0 = (const float*)d_in[5];
  const float* bih0 = (const float*)d_in[6];
  const float* bhh0 = (const float*)d_in[7];
  const float* Wih1 = (const float*)d_in[8];
  const float* Whh1 = (const float*)d_in[9];
  const float* bih1 = (const float*)d_in[10];
  const float* bhh1 = (const float*)d_in[11];
  const float* Wlin = (const float*)d_in[12];
  const float* blin = (const float*)d_in[13];
  uint32_t* ws = (uint32_t*)d_ws;
  float* alpha = (float*)(ws + 103424);
  float* out = (float*)d_out;

  prep_kernel<<<404, 256, 0, stream>>>(Wih0, Whh0, bih0, bhh0, Wih1, Whh1, bih1, bhh1, ws);
  lstm_kernel<<<256, 512, 0, stream>>>(a, a0, ws, Wlin, blin, alpha);
  kalman_kernel<<<512, 256, 0, stream>>>(a, A, C, alpha, out);
}

// Round 8
// 1048.211 us; speedup vs baseline: 1.4529x; 1.0192x over previous
//
#include <hip/hip_runtime.h>
#include <hip/hip_fp16.h>
#include <cstdint>

#define T_LEN 128
#define DA    16
#define DZ    32
#define HH    128

__device__ __forceinline__ float sigm(float x){ return 1.0f/(1.0f + __expf(-x)); }
__device__ __forceinline__ float tanh_f(float x){ return 1.0f - 2.0f/(__expf(2.0f*x)+1.0f); }

typedef _Float16 h2v __attribute__((ext_vector_type(2)));
__device__ __forceinline__ float fdot2(uint32_t w, uint32_t h, float acc){
  union{uint32_t u; h2v v;} a, b; a.u = w; b.u = h;
  return __builtin_amdgcn_fdot2(a.v, b.v, acc, false);
}
__device__ __forceinline__ uint32_t packh2(float x, float y){
  return (uint32_t)__half_as_ushort(__float2half(x)) |
         ((uint32_t)__half_as_ushort(__float2half(y)) << 16);
}
__device__ __forceinline__ float h2lo(uint32_t u){
  return __half2float(__ushort_as_half((unsigned short)(u & 0xffffu)));
}
__device__ __forceinline__ float h2hi(uint32_t u){
  return __half2float(__ushort_as_half((unsigned short)(u >> 16)));
}
__device__ __forceinline__ float dot8(uint4 a, uint4 b, float acc){
  acc = fdot2(a.x, b.x, acc); acc = fdot2(a.y, b.y, acc);
  acc = fdot2(a.z, b.z, acc); acc = fdot2(a.w, b.w, acc);
  return acc;
}
__device__ __forceinline__ float dot8f(uint4 h, float4 f0, float4 f1, float acc){
  acc += h2lo(h.x)*f0.x + h2hi(h.x)*f0.y + h2lo(h.y)*f0.z + h2hi(h.y)*f0.w;
  acc += h2lo(h.z)*f1.x + h2hi(h.z)*f1.y + h2lo(h.w)*f1.z + h2hi(h.w)*f1.w;
  return acc;
}

// LDS-only barrier: drain LDS pipe, raw s_barrier (no vmcnt drain).
#define BAR() do { asm volatile("s_waitcnt lgkmcnt(0)" ::: "memory"); \
                   __builtin_amdgcn_s_barrier(); } while (0)

__global__ void prep_kernel(const float* __restrict__ Wih0, const float* __restrict__ Whh0,
                            const float* __restrict__ bih0, const float* __restrict__ bhh0,
                            const float* __restrict__ Wih1, const float* __restrict__ Whh1,
                            const float* __restrict__ bih1, const float* __restrict__ bhh1,
                            uint32_t* __restrict__ ws) {
  int idx = blockIdx.x*256 + threadIdx.x;
  if (idx < 4096) {
    int q = idx & 3, g = (idx >> 2) & 511, m = idx >> 11;
    int k0 = 8*m + 2*q;
    ws[idx] = packh2(Wih0[g*DA + k0], Wih0[g*DA + k0 + 1]);
  } else if (idx < 36864) {
    int f = idx - 4096;
    int q = f & 3, g = (f >> 2) & 511, m = f >> 11;
    int k0 = 8*m + 2*q;
    ws[idx] = packh2(Whh0[g*HH + k0], Whh0[g*HH + k0 + 1]);
  } else if (idx < 69632) {
    int f = idx - 36864;
    int q = f & 3, g = (f >> 2) & 511, m = f >> 11;
    int k0 = 8*m + 2*q;
    ws[idx] = packh2(Wih1[g*HH + k0], Wih1[g*HH + k0 + 1]);
  } else if (idx < 102400) {
    int f = idx - 69632;
    int q = f & 3, g = (f >> 2) & 511, m = f >> 11;
    int k0 = 8*m + 2*q;
    ws[idx] = packh2(Whh1[g*HH + k0], Whh1[g*HH + k0 + 1]);
  } else if (idx < 102912) {
    int j = idx - 102400;
    ((float*)ws)[idx] = bih0[j] + bhh0[j];
  } else if (idx < 103424) {
    int j = idx - 102912;
    ((float*)ws)[idx] = bih1[j] + bhh1[j];
  }
}

// Persistent 2-layer LSTM. Round-8: B4 + head phase deleted (4 barriers/step).
// act1 folds per-cell logit contributions in-register (6x3 shfl_down), lane-0
// writes 4x3 wave partials to hpart; finalize (2 threads of wave 7) is
// deferred past B1 of t+1, which orders the partials. t=127 flushed after
// the loop. B4 removal is safe: act1's sh1h is next read by gates1(t+1),
// already ordered by B1+B2 of t+1.
__global__ __launch_bounds__(512, 2) void lstm_kernel(
    const float* __restrict__ a, const float* __restrict__ a0,
    const uint32_t* __restrict__ wsw, const float* __restrict__ Wlin,
    const float* __restrict__ blin, float* __restrict__ alpha_out) {
  const uint4* Wih0p = (const uint4*)(wsw);
  const uint4* Whh0p = (const uint4*)(wsw + 4096);
  const uint4* Wih1p = (const uint4*)(wsw + 36864);
  const uint4* Whh1p = (const uint4*)(wsw + 69632);
  const float* b0v = (const float*)(wsw + 102400);
  const float* b1v = (const float*)(wsw + 102912);

  __shared__ __align__(16) uint32_t sxh[2][T_LEN][8];
  __shared__ __align__(16) uint32_t sh0h[2][64];
  __shared__ __align__(16) uint32_t sh1h[2][64];
  __shared__ float gates[2][4*HH];
  __shared__ float hpart[4][3];

  int tid = threadIdx.x;
  int lane = tid & 63;
  int wv = tid >> 6;
  int bb = blockIdx.x * 2;

  uint4 wi0[2], wh0[16], wi1[16], wh1[16];
  #pragma unroll
  for (int m = 0; m < 2; ++m)  wi0[m] = Wih0p[m*512 + tid];
  #pragma unroll
  for (int m = 0; m < 16; ++m) wh0[m] = Whh0p[m*512 + tid];
  #pragma unroll
  for (int m = 0; m < 16; ++m) wi1[m] = Wih1p[m*512 + tid];
  #pragma unroll
  for (int m = 0; m < 16; ++m) wh1[m] = Whh1p[m*512 + tid];
  float bi0 = b0v[tid], bi1 = b1v[tid];

  for (int i = tid; i < 2*T_LEN*8; i += 512) {
    int r = i / (T_LEN*8), rem = i % (T_LEN*8), t = rem >> 3, p = rem & 7;
    float x0, x1;
    if (t == 0) { x0 = a0[2*p]; x1 = a0[2*p+1]; }
    else {
      const float* src = a + ((size_t)(bb + r)*T_LEN + (t-1))*DA;
      x0 = src[2*p]; x1 = src[2*p+1];
    }
    sxh[r][t][p] = packh2(x0, x1);
  }
  // per-cell head weights (used by tid<256; cell = tid&127)
  float wl0 = Wlin[0*HH + (tid & 127)];
  float wl1 = Wlin[1*HH + (tid & 127)];
  float wl2 = Wlin[2*HH + (tid & 127)];
  float bl0 = blin[0], bl1 = blin[1], bl2 = blin[2];
  float cl0 = 0.f, cl1 = 0.f;
  if (tid < 128) { sh0h[wv][lane] = 0u; sh1h[wv][lane] = 0u; }
  __syncthreads();

  #pragma unroll 1
  for (int t = 0; t < T_LEN; ++t) {
    {
      float g0a = bi0, g0b = 0.f, g1a = bi0, g1b = 0.f;
      uint4 xA0 = *(const uint4*)&sxh[0][t][0];
      uint4 xA1 = *(const uint4*)&sxh[0][t][4];
      uint4 xB0 = *(const uint4*)&sxh[1][t][0];
      uint4 xB1 = *(const uint4*)&sxh[1][t][4];
      g0a = fdot2(wi0[0].x, xA0.x, g0a); g0b = fdot2(wi0[0].y, xA0.y, g0b);
      g0a = fdot2(wi0[0].z, xA0.z, g0a); g0b = fdot2(wi0[0].w, xA0.w, g0b);
      g0a = fdot2(wi0[1].x, xA1.x, g0a); g0b = fdot2(wi0[1].y, xA1.y, g0b);
      g0a = fdot2(wi0[1].z, xA1.z, g0a); g0b = fdot2(wi0[1].w, xA1.w, g0b);
      g1a = fdot2(wi0[0].x, xB0.x, g1a); g1b = fdot2(wi0[0].y, xB0.y, g1b);
      g1a = fdot2(wi0[0].z, xB0.z, g1a); g1b = fdot2(wi0[0].w, xB0.w, g1b);
      g1a = fdot2(wi0[1].x, xB1.x, g1a); g1b = fdot2(wi0[1].y, xB1.y, g1b);
      g1a = fdot2(wi0[1].z, xB1.z, g1a); g1b = fdot2(wi0[1].w, xB1.w, g1b);
      #pragma unroll
      for (int m = 0; m < 16; ++m) {
        uint4 w = wh0[m];
        uint4 hA = *(const uint4*)&sh0h[0][4*m];
        uint4 hB = *(const uint4*)&sh0h[1][4*m];
        g0a = fdot2(w.x, hA.x, g0a); g0b = fdot2(w.y, hA.y, g0b);
        g0a = fdot2(w.z, hA.z, g0a); g0b = fdot2(w.w, hA.w, g0b);
        g1a = fdot2(w.x, hB.x, g1a); g1b = fdot2(w.y, hB.y, g1b);
        g1a = fdot2(w.z, hB.z, g1a); g1b = fdot2(w.w, hB.w, g1b);
      }
      gates[0][tid] = g0a + g0b;
      gates[1][tid] = g1a + g1b;
    }
    __syncthreads();                                   // B1
    // deferred head finalize for step t-1 (hpart ordered by B1)
    if (t > 0 && tid >= 504 && tid < 506) {
      int row = tid - 504;
      float l0 = hpart[2*row][0] + hpart[2*row+1][0] + bl0;
      float l1 = hpart[2*row][1] + hpart[2*row+1][1] + bl1;
      float l2 = hpart[2*row][2] + hpart[2*row+1][2] + bl2;
      float mx = fmaxf(l0, fmaxf(l1, l2));
      float e0=__expf(l0-mx), e1=__expf(l1-mx), e2=__expf(l2-mx);
      float inv = 1.0f/(e0+e1+e2);
      float* dst = alpha_out + (((size_t)(bb+row))*T_LEN + (t-1))*3;
      dst[0]=e0*inv; dst[1]=e1*inv; dst[2]=e2*inv;
    }
    if (tid < 256) {
      int row = tid >> 7, cell = tid & 127;
      float iv = gates[row][cell],      fv = gates[row][cell+HH],
            qv = gates[row][cell+2*HH], ov = gates[row][cell+3*HH];
      cl0 = sigm(fv)*cl0 + sigm(iv)*tanh_f(qv);
      float hv = sigm(ov)*tanh_f(cl0);
      ((__half*)&sh0h[0][0])[row*128 + cell] = __float2half(hv);
    }
    __syncthreads();                                   // B2
    {
      float g0a = bi1, g0b = 0.f, g1a = bi1, g1b = 0.f;
      #pragma unroll
      for (int m = 0; m < 16; ++m) {
        uint4 w = wi1[m];
        uint4 hA = *(const uint4*)&sh0h[0][4*m];
        uint4 hB = *(const uint4*)&sh0h[1][4*m];
        g0a = fdot2(w.x, hA.x, g0a); g0b = fdot2(w.y, hA.y, g0b);
        g0a = fdot2(w.z, hA.z, g0a); g0b = fdot2(w.w, hA.w, g0b);
        g1a = fdot2(w.x, hB.x, g1a); g1b = fdot2(w.y, hB.y, g1b);
        g1a = fdot2(w.z, hB.z, g1a); g1b = fdot2(w.w, hB.w, g1b);
      }
      #pragma unroll
      for (int m = 0; m < 16; ++m) {
        uint4 w = wh1[m];
        uint4 hA = *(const uint4*)&sh1h[0][4*m];
        uint4 hB = *(const uint4*)&sh1h[1][4*m];
        g0a = fdot2(w.x, hA.x, g0a); g0b = fdot2(w.y, hA.y, g0b);
        g0a = fdot2(w.z, hA.z, g0a); g0b = fdot2(w.w, hA.w, g0b);
        g1a = fdot2(w.x, hB.x, g1a); g1b = fdot2(w.y, hB.y, g1b);
        g1a = fdot2(w.z, hB.z, g1a); g1b = fdot2(w.w, hB.w, g1b);
      }
      gates[0][tid] = g0a + g0b;
      gates[1][tid] = g1a + g1b;
    }
    __syncthreads();                                   // B3
    if (tid < 256) {
      int row = tid >> 7, cell = tid & 127;
      float iv = gates[row][cell],      fv = gates[row][cell+HH],
            qv = gates[row][cell+2*HH], ov = gates[row][cell+3*HH];
      cl1 = sigm(fv)*cl1 + sigm(iv)*tanh_f(qv);
      float hv = sigm(ov)*tanh_f(cl1);
      ((__half*)&sh1h[0][0])[row*128 + cell] = __float2half(hv);
      // head partials in-register; lane 0 writes per-wave sums
      float p0 = hv*wl0, p1 = hv*wl1, p2 = hv*wl2;
      #pragma unroll
      for (int off = 32; off > 0; off >>= 1) {
        p0 += __shfl_down(p0, off); p1 += __shfl_down(p1, off); p2 += __shfl_down(p2, off);
      }
      if (lane == 0) {
        int w4 = tid >> 6;
        hpart[w4][0] = p0; hpart[w4][1] = p1; hpart[w4][2] = p2;
      }
    }
    // no barrier: sh1h next read is gates1(t+1) behind B1+B2; hpart finalize
    // is behind B1(t+1).
  }
  __syncthreads();                                     // flush for t=127
  if (tid >= 504 && tid < 506) {
    int row = tid - 504;
    float l0 = hpart[2*row][0] + hpart[2*row+1][0] + bl0;
    float l1 = hpart[2*row][1] + hpart[2*row+1][1] + bl1;
    float l2 = hpart[2*row][2] + hpart[2*row+1][2] + bl2;
    float mx = fmaxf(l0, fmaxf(l1, l2));
    float e0=__expf(l0-mx), e1=__expf(l1-mx), e2=__expf(l2-mx);
    float inv = 1.0f/(e0+e1+e2);
    float* dst = alpha_out + (((size_t)(bb+row))*T_LEN + (T_LEN-1))*3;
    dst[0]=e0*inv; dst[1]=e1*inv; dst[2]=e2*inv;
  }
}

// Kalman scan v11 = v9 arithmetic (known-good), mix phase folded into P7 with
// double-buffered AmH/CmH (parity t&1): 7 barriers/step instead of 8. The
// v10 lesson: relocate the schedule, never the algebra.
__global__ __launch_bounds__(256) void kalman_kernel(
    const float* __restrict__ a, const float* __restrict__ A,
    const float* __restrict__ C, const float* __restrict__ alpha,
    float* __restrict__ out) {
  __shared__ __align__(16) uint32_t SgH[DZ][20];
  __shared__ __align__(16) uint32_t AmH[2][DZ][20];
  __shared__ __align__(16) uint32_t CmH[2][DA][20];
  __shared__ __align__(16) uint32_t Sp2H[DZ][20];
  __shared__ __align__(16) uint32_t T2H[DZ][20];
  __shared__ __align__(16) uint32_t NnTH[DA][20];
  __shared__ __align__(16) uint32_t NnH[DZ][12];
  __shared__ __align__(16) uint32_t KgH[DZ][12];
  __shared__ __align__(16) uint32_t SinvH[DA][12];
  __shared__ __align__(16) float Aug[DA][36];
  __shared__ __align__(16) float sa[T_LEN][DA];
  __shared__ float salpha[T_LEN*3];
  __shared__ __align__(16) float muvF[DZ], munF[DZ], rv[DA];

  int tid = threadIdx.x;
  int b = blockIdx.x;

  for (int e = tid; e < T_LEN*DA; e += 256) (&sa[0][0])[e] = a[(size_t)b*T_LEN*DA + e];
  for (int e = tid; e < T_LEN*3; e += 256) salpha[e] = alpha[(size_t)b*T_LEN*3 + e];
  __syncthreads();

  const int i8 = tid >> 3, jq = tid & 7;
  const int i32 = tid & 31, g = tid >> 5;
  const int j2 = g * 2, j4 = g * 4;

  {
    uint2 iv;
    iv.x = packh2((i8==4*jq  )?1.f:0.f, (i8==4*jq+1)?1.f:0.f);
    iv.y = packh2((i8==4*jq+2)?1.f:0.f, (i8==4*jq+3)?1.f:0.f);
    *(uint2*)&SgH[i8][jq*2] = iv;
    if (tid < DZ) muvF[tid] = 0.0f;
  }

  const float4* A4 = (const float4*)A;
  const float4* C4 = (const float4*)C;
  // prefetch for mix(s=0): A @ ta(0)=1, C @ 0
  float4 pA0 = A4[(0*T_LEN + 1)*256 + tid];
  float4 pA1 = A4[(1*T_LEN + 1)*256 + tid];
  float4 pA2 = A4[(2*T_LEN + 1)*256 + tid];
  float4 pC0, pC1, pC2;
  if (tid < 128) {
    pC0 = C4[(0*T_LEN + 0)*128 + tid];
    pC1 = C4[(1*T_LEN + 0)*128 + tid];
    pC2 = C4[(2*T_LEN + 0)*128 + tid];
  }
  // MIX(s) into buffer bf, consuming pA*/pC*; then load prefetch for step sn.
  #define MIX_AND_PREFETCH(bf, s, sn)                                          \
  {                                                                            \
    int ta_ = ((s) < T_LEN-1) ? (s)+1 : (s);                                   \
    float bA0 = salpha[ta_*3+0], bA1 = salpha[ta_*3+1], bA2 = salpha[ta_*3+2]; \
    float bC0 = salpha[(s)*3+0], bC1 = salpha[(s)*3+1], bC2 = salpha[(s)*3+2]; \
    float vx = bA0*pA0.x + bA1*pA1.x + bA2*pA2.x;                              \
    float vy = bA0*pA0.y + bA1*pA1.y + bA2*pA2.y;                              \
    float vz = bA0*pA0.z + bA1*pA1.z + bA2*pA2.z;                              \
    float vw = bA0*pA0.w + bA1*pA1.w + bA2*pA2.w;                              \
    uint2 pv; pv.x = packh2(vx, vy); pv.y = packh2(vz, vw);                    \
    *(uint2*)&AmH[bf][i8][jq*2] = pv;                                          \
    if (tid < 128) {                                                           \
      float cx = bC0*pC0.x + bC1*pC1.x + bC2*pC2.x;                            \
      float cy = bC0*pC0.y + bC1*pC1.y + bC2*pC2.y;                            \
      float cz = bC0*pC0.z + bC1*pC1.z + bC2*pC2.z;                            \
      float cw = bC0*pC0.w + bC1*pC1.w + bC2*pC2.w;                            \
      uint2 pc; pc.x = packh2(cx, cy); pc.y = packh2(cz, cw);                  \
      *(uint2*)&CmH[bf][tid>>3][(tid&7)*2] = pc;                               \
    }                                                                          \
    int sn_ = ((sn) < T_LEN) ? (sn) : T_LEN-1;                                 \
    int tan_ = (sn_ < T_LEN-1) ? sn_+1 : sn_;                                  \
    pA0 = A4[(0*T_LEN + tan_)*256 + tid];                                      \
    pA1 = A4[(1*T_LEN + tan_)*256 + tid];                                      \
    pA2 = A4[(2*T_LEN + tan_)*256 + tid];                                      \
    if (tid < 128) {                                                           \
      pC0 = C4[(0*T_LEN + sn_)*128 + tid];                                     \
      pC1 = C4[(1*T_LEN + sn_)*128 + tid];                                     \
      pC2 = C4[(2*T_LEN + sn_)*128 + tid];                                     \
    }                                                                          \
  }

  // pre-loop: mix step 0 into buffer 0; prefetch step 1
  MIX_AND_PREFETCH(0, 0, 1)
  __syncthreads();

  #pragma unroll 1
  for (int t = 0; t < T_LEN; ++t) {
    const int p = t & 1;

    // ---- P1: N[i][j] = dot(Sg_i, Cm_j) (strip2); NnT scatter ----
    {
      uint4 s0 = *(const uint4*)&SgH[i32][0];
      uint4 s1 = *(const uint4*)&SgH[i32][4];
      uint4 s2 = *(const uint4*)&SgH[i32][8];
      uint4 s3 = *(const uint4*)&SgH[i32][12];
      uint4 cA0 = *(const uint4*)&CmH[p][j2][0];
      uint4 cA1 = *(const uint4*)&CmH[p][j2][4];
      uint4 cA2 = *(const uint4*)&CmH[p][j2][8];
      uint4 cA3 = *(const uint4*)&CmH[p][j2][12];
      uint4 cB0 = *(const uint4*)&CmH[p][j2+1][0];
      uint4 cB1 = *(const uint4*)&CmH[p][j2+1][4];
      uint4 cB2 = *(const uint4*)&CmH[p][j2+1][8];
      uint4 cB3 = *(const uint4*)&CmH[p][j2+1][12];
      float aA = dot8(s3,cA3, dot8(s2,cA2, dot8(s1,cA1, dot8(s0,cA0, 0.f))));
      float aB = dot8(s3,cB3, dot8(s2,cB2, dot8(s1,cB1, dot8(s0,cB0, 0.f))));
      NnH[i32][g] = packh2(aA, aB);
      __half* ntp = (__half*)&NnTH[0][0];
      ntp[j2*40 + i32]     = __float2half(aA);
      ntp[(j2+1)*40 + i32] = __float2half(aB);
    }
    BAR();                                             // B1

    // ---- P2: Aug = [Cm*Sg*Cm^T + R | I] ----
    {
      int i = tid & 15, j = tid >> 4;
      uint4 c0 = *(const uint4*)&CmH[p][i][0];
      uint4 c1 = *(const uint4*)&CmH[p][i][4];
      uint4 c2 = *(const uint4*)&CmH[p][i][8];
      uint4 c3 = *(const uint4*)&CmH[p][i][12];
      uint4 n0 = *(const uint4*)&NnTH[j][0];
      uint4 n1 = *(const uint4*)&NnTH[j][4];
      uint4 n2 = *(const uint4*)&NnTH[j][8];
      uint4 n3 = *(const uint4*)&NnTH[j][12];
      float s = dot8(c3,n3, dot8(c2,n2, dot8(c1,n1, dot8(c0,n0, 0.f))));
      Aug[i][j] = s + ((i == j) ? 0.01f : 0.0f);
      Aug[i][16 + j] = (i == j) ? 1.0f : 0.0f;
    }
    BAR();                                             // B2

    // ---- P3: GJ (wave 0) -> Sinv h2; r (wave 1) ----
    if (tid < 64) {
      int lane = tid;
      int r = lane >> 2, cb = lane & 3;
      float v[8];
      #pragma unroll
      for (int j = 0; j < 8; ++j) v[j] = Aug[r][cb*8 + j];
      #define GJ_PIVOT(P, CTRL)                                                \
      {                                                                        \
        float App = __int_as_float(__builtin_amdgcn_readlane(                  \
                      __float_as_int(v[(P) & 7]), ((P) << 2) | ((P) >> 3)));   \
        float fv  = __int_as_float(__builtin_amdgcn_mov_dpp(                   \
                      __float_as_int(v[(P) & 7]), (CTRL), 0xf, 0xf, true));    \
        float prow[8];                                                         \
        _Pragma("unroll")                                                      \
        for (int j = 0; j < 8; ++j) prow[j] = __shfl(v[j], ((P) << 2) | cb, 64); \
        float pinv = 1.0f / App;                                               \
        if (r == (P)) {                                                        \
          _Pragma("unroll")                                                    \
          for (int j = 0; j < 8; ++j) v[j] *= pinv;                            \
        } else {                                                               \
          float fp = fv * pinv;                                                \
          _Pragma("unroll")                                                    \
          for (int j = 0; j < 8; ++j) v[j] -= fp * prow[j];                    \
        }                                                                      \
      }
      GJ_PIVOT(0, 0x00)  GJ_PIVOT(1, 0x00)  GJ_PIVOT(2, 0x00)  GJ_PIVOT(3, 0x00)
      GJ_PIVOT(4, 0x00)  GJ_PIVOT(5, 0x00)  GJ_PIVOT(6, 0x00)  GJ_PIVOT(7, 0x00)
      GJ_PIVOT(8, 0x55)  GJ_PIVOT(9, 0x55)  GJ_PIVOT(10, 0x55) GJ_PIVOT(11, 0x55)
      GJ_PIVOT(12, 0x55) GJ_PIVOT(13, 0x55) GJ_PIVOT(14, 0x55) GJ_PIVOT(15, 0x55)
      #undef GJ_PIVOT
      if (cb >= 2) {
        uint4 w;
        w.x = packh2(v[0], v[1]); w.y = packh2(v[2], v[3]);
        w.z = packh2(v[4], v[5]); w.w = packh2(v[6], v[7]);
        *(uint4*)&SinvH[r][(cb-2)*4] = w;
      }
    } else if (tid < 64 + DA) {
      int j = tid - 64;
      uint4 c0 = *(const uint4*)&CmH[p][j][0];
      uint4 c1 = *(const uint4*)&CmH[p][j][4];
      uint4 c2 = *(const uint4*)&CmH[p][j][8];
      uint4 c3 = *(const uint4*)&CmH[p][j][12];
      const float4* mv = (const float4*)muvF;
      float4 m0 = mv[0], m1 = mv[1], m2 = mv[2], m3 = mv[3];
      float4 m4 = mv[4], m5 = mv[5], m6 = mv[6], m7 = mv[7];
      float d = 0.f;
      d = dot8f(c0, m0, m1, d);
      d = dot8f(c1, m2, m3, d);
      d = dot8f(c2, m4, m5, d);
      d = dot8f(c3, m6, m7, d);
      rv[j] = sa[t][j] - d;
    }
    BAR();                                             // B3

    // ---- P4: Kg[i][j] = dot(Nn_i, Sinv_j) (strip2) ----
    {
      uint4 n0 = *(const uint4*)&NnH[i32][0];
      uint4 n1 = *(const uint4*)&NnH[i32][4];
      uint4 sA0 = *(const uint4*)&SinvH[j2][0];
      uint4 sA1 = *(const uint4*)&SinvH[j2][4];
      uint4 sB0 = *(const uint4*)&SinvH[j2+1][0];
      uint4 sB1 = *(const uint4*)&SinvH[j2+1][4];
      float aA = dot8(n1, sA1, dot8(n0, sA0, 0.f));
      float aB = dot8(n1, sB1, dot8(n0, sB0, 0.f));
      KgH[i32][g] = packh2(aA, aB);
    }
    BAR();                                             // B4

    // ---- P5: Sp2 = Sg - Kg*Nn^T (strip4); mu+ & out on wave 2 ----
    {
      uint4 k0 = *(const uint4*)&KgH[i32][0];
      uint4 k1 = *(const uint4*)&KgH[i32][4];
      float acc[4];
      #pragma unroll
      for (int c = 0; c < 4; ++c) {
        uint4 b0 = *(const uint4*)&NnH[j4+c][0];
        uint4 b1 = *(const uint4*)&NnH[j4+c][4];
        acc[c] = dot8(k1, b1, dot8(k0, b0, 0.f));
      }
      uint2 sgp = *(const uint2*)&SgH[i32][g*2];
      uint2 o;
      o.x = packh2(h2lo(sgp.x) - acc[0], h2hi(sgp.x) - acc[1]);
      o.y = packh2(h2lo(sgp.y) - acc[2], h2hi(sgp.y) - acc[3]);
      *(uint2*)&Sp2H[i32][g*2] = o;
    }
    if (tid >= 128 && tid < 128 + DZ) {
      int q = tid - 128;
      uint4 k0 = *(const uint4*)&KgH[q][0];
      uint4 k1 = *(const uint4*)&KgH[q][4];
      const float4* rp = (const float4*)rv;
      float4 r0 = rp[0], r1 = rp[1], r2 = rp[2], r3 = rp[3];
      float m = muvF[q];
      m = dot8f(k0, r0, r1, m);
      m = dot8f(k1, r2, r3, m);
      munF[q] = m;
      out[((size_t)b*T_LEN + t)*DZ + q] = m;
    }
    BAR();                                             // B5

    // ---- P6: T2[i][j] = dot(Am_i, Sp2_j) (strip4) ----
    {
      uint4 a0 = *(const uint4*)&AmH[p][i32][0];
      uint4 a1 = *(const uint4*)&AmH[p][i32][4];
      uint4 a2 = *(const uint4*)&AmH[p][i32][8];
      uint4 a3 = *(const uint4*)&AmH[p][i32][12];
      float acc[4];
      #pragma unroll
      for (int c = 0; c < 4; ++c) {
        uint4 p0 = *(const uint4*)&Sp2H[j4+c][0];
        uint4 p1 = *(const uint4*)&Sp2H[j4+c][4];
        uint4 p2 = *(const uint4*)&Sp2H[j4+c][8];
        uint4 p3 = *(const uint4*)&Sp2H[j4+c][12];
        acc[c] = dot8(a3,p3, dot8(a2,p2, dot8(a1,p1, dot8(a0,p0, 0.f))));
      }
      uint2 o; o.x = packh2(acc[0], acc[1]); o.y = packh2(acc[2], acc[3]);
      *(uint2*)&T2H[i32][g*2] = o;
    }
    BAR();                                             // B6

    // ---- P7: Sg' = T2*Am^T + Q (strip4); mu_pred (wave 2);
    //          MIX(t+1) into buffer p^1 + prefetch(t+2) ----
    {
      uint4 t0 = *(const uint4*)&T2H[i32][0];
      uint4 t1 = *(const uint4*)&T2H[i32][4];
      uint4 t2 = *(const uint4*)&T2H[i32][8];
      uint4 t3 = *(const uint4*)&T2H[i32][12];
      float acc[4];
      #pragma unroll
      for (int c = 0; c < 4; ++c) {
        uint4 a0 = *(const uint4*)&AmH[p][j4+c][0];
        uint4 a1 = *(const uint4*)&AmH[p][j4+c][4];
        uint4 a2 = *(const uint4*)&AmH[p][j4+c][8];
        uint4 a3 = *(const uint4*)&AmH[p][j4+c][12];
        acc[c] = dot8(t3,a3, dot8(t2,a2, dot8(t1,a1, dot8(t0,a0, 0.f))));
        if (i32 == j4 + c) acc[c] += 0.01f;
      }
      uint2 o; o.x = packh2(acc[0], acc[1]); o.y = packh2(acc[2], acc[3]);
      *(uint2*)&SgH[i32][g*2] = o;
    }
    if (tid >= 128 && tid < 128 + DZ) {
      int q = tid - 128;
      uint4 a0 = *(const uint4*)&AmH[p][q][0];
      uint4 a1 = *(const uint4*)&AmH[p][q][4];
      uint4 a2 = *(const uint4*)&AmH[p][q][8];
      uint4 a3 = *(const uint4*)&AmH[p][q][12];
      const float4* mp = (const float4*)munF;
      float4 n0 = mp[0], n1 = mp[1], n2 = mp[2], n3 = mp[3];
      float4 n4 = mp[4], n5 = mp[5], n6 = mp[6], n7 = mp[7];
      float m = 0.f;
      m = dot8f(a0, n0, n1, m);
      m = dot8f(a1, n2, n3, m);
      m = dot8f(a2, n4, n5, m);
      m = dot8f(a3, n6, n7, m);
      muvF[q] = m;
    }
    {
      int s = (t+1 < T_LEN) ? t+1 : T_LEN-1;
      MIX_AND_PREFETCH(p^1, s, t+2)
    }
    BAR();                                             // B7
  }
  #undef MIX_AND_PREFETCH
}

extern "C" void kernel_launch(void* const* d_in, const int* in_sizes, int n_in,
                              void* d_out, int out_size, void* d_ws, size_t ws_size,
                              hipStream_t stream) {
  const float* a    = (const float*)d_in[0];
  const float* A    = (const float*)d_in[1];
  const float* C    = (const float*)d_in[2];
  const float* a0   = (const float*)d_in[3];
  const float* Wih0 = (const float*)d_in[4];
  const float* Whh0 = (const float*)d_in[5];
  const float* bih0 = (const float*)d_in[6];
  const float* bhh0 = (const float*)d_in[7];
  const float* Wih1 = (const float*)d_in[8];
  const float* Whh1 = (const float*)d_in[9];
  const float* bih1 = (const float*)d_in[10];
  const float* bhh1 = (const float*)d_in[11];
  const float* Wlin = (const float*)d_in[12];
  const float* blin = (const float*)d_in[13];
  uint32_t* ws = (uint32_t*)d_ws;
  float* alpha = (float*)(ws + 103424);
  float* out = (float*)d_out;

  prep_kernel<<<404, 256, 0, stream>>>(Wih0, Whh0, bih0, bhh0, Wih1, Whh1, bih1, bhh1, ws);
  lstm_kernel<<<256, 512, 0, stream>>>(a, a0, ws, Wlin, blin, alpha);
  kalman_kernel<<<512, 256, 0, stream>>>(a, A, C, alpha, out);
}